// Round 5
// baseline (233.353 us; speedup 1.0000x reference)
//
#include <hip/hip_runtime.h>

typedef float f32x4 __attribute__((ext_vector_type(4)));
typedef float f32x16 __attribute__((ext_vector_type(16)));
typedef __bf16 bf16x8 __attribute__((ext_vector_type(8)));
typedef unsigned short u16x8 __attribute__((ext_vector_type(8)));
typedef int i32x2 __attribute__((ext_vector_type(2)));
typedef int i32x4 __attribute__((ext_vector_type(4)));

#define DEV static __device__ __forceinline__

DEV float bf2f(unsigned short h) {
  unsigned int u = ((unsigned int)h) << 16;
  return __builtin_bit_cast(float, u);
}
DEV unsigned short f2bf(float f) {
  unsigned int u = __builtin_bit_cast(unsigned int, f);
  u += 0x7fff + ((u >> 16) & 1);   // RTNE
  return (unsigned short)(u >> 16);
}

DEV void g2l16(const void* g, void* l) {
  __builtin_amdgcn_global_load_lds(
      (const __attribute__((address_space(1))) void*)g,
      (__attribute__((address_space(3))) void*)l, 16, 0, 0);
}

template <int N> DEV void vm_wait() {
  asm volatile("s_waitcnt vmcnt(%0)" ::"n"(N) : "memory");
}
DEV void hard_barrier() {
  __builtin_amdgcn_s_barrier();
  __builtin_amdgcn_sched_barrier(0);  // pin: nothing crosses the barrier
}

DEV unsigned int cvtpk(float lo, float hi) {
  unsigned int r;
  asm("v_cvt_pk_bf16_f32 %0, %1, %2" : "=v"(r) : "v"(lo), "v"(hi));
  return r;
}

// ---------------- fp32 -> bf16 convert (n % 8 == 0) ----------------
__global__ __launch_bounds__(256) void k_cvt(const float* __restrict__ in,
                                             unsigned short* __restrict__ out, int n) {
  int i = (blockIdx.x * 256 + threadIdx.x) * 8;
  if (i >= n) return;
  float4 a = *(const float4*)(in + i);
  float4 b = *(const float4*)(in + i + 4);
  u16x8 r;
  r[0] = f2bf(a.x); r[1] = f2bf(a.y); r[2] = f2bf(a.z); r[3] = f2bf(a.w);
  r[4] = f2bf(b.x); r[5] = f2bf(b.y); r[6] = f2bf(b.z); r[7] = f2bf(b.w);
  *(u16x8*)(out + i) = r;
}

// ---------------- NT GEMM, counted-vmcnt 2-phase pipeline ----------------
// C[M,N] = A[M,K] * B[N,K]^T. 512 threads (8 waves: 2m x 4n), BK=64.
// Ledger (issues of 8KB each): stageB = NBI, stageA half = ABI.
// phase0(t): wait vmcnt(ABI)  [A1(t) in flight]; stage B(t+1); read B(t),A0(t)
// phase1(t): wait vmcnt(NBI)  [B(t+1) in flight]; stage A(t+1); read A1(t)
template <int BM, int BN, typename OUT>
__global__ __launch_bounds__(512, 1) void k_gemm8(const unsigned short* __restrict__ A,
                                                  const unsigned short* __restrict__ B,
                                                  OUT* __restrict__ C, int M, int N, int K) {
  constexpr int MR = BM / 32;       // per-wave m-frags
  constexpr int MH = MR / 2;        // m-frags per phase
  constexpr int FN = BN >> 6;       // per-wave n-frags
  constexpr int NBI = (BN * 128) / 8192;       // B issues per tile
  constexpr int ABI = (BM * 128) / 8192 / 2;   // A issues per half-tile
  __shared__ unsigned short sA[2][BM * 64];
  __shared__ unsigned short sB[2][BN * 64];
  const int tid = threadIdx.x;
  const int wid = tid >> 6, lane = tid & 63;
  const int wm = wid >> 2, wn = wid & 3;
  const int g = lane >> 4, r16 = lane & 15;
  const int m0 = blockIdx.x * BM, n0 = blockIdx.y * BN;
  const int NK = K >> 6;

  const int srow = (wid << 3) + (lane >> 3);
  const int scolb = (lane & 7) << 4;

  f32x4 acc[MR][FN];
#pragma unroll
  for (int i = 0; i < MR; ++i)
#pragma unroll
    for (int j = 0; j < FN; ++j) acc[i][j] = f32x4{0.f, 0.f, 0.f, 0.f};

  auto stageB = [&](int kt, int buf) {
    const unsigned short* gb = B + (size_t)n0 * K + (kt << 6);
#pragma unroll
    for (int c = 0; c < NBI; ++c) {
      int r = c * 64 + srow;
      int sc = scolb ^ ((r & 7) << 4);
      g2l16((const char*)(gb + (size_t)r * K) + sc, (char*)&sB[buf][0] + c * 8192 + wid * 1024);
    }
  };
  auto stageA = [&](int kt, int buf, int part) {
    const unsigned short* ga = A + (size_t)m0 * K + (kt << 6);
    if constexpr (BM == 256) {
#pragma unroll
      for (int c = 0; c < 2; ++c) {
        int r = c * 128 + part * 64 + srow;
        int sc = scolb ^ ((r & 7) << 4);
        g2l16((const char*)(ga + (size_t)r * K) + sc,
              (char*)&sA[buf][0] + c * 16384 + part * 8192 + wid * 1024);
      }
    } else {
      int rb = (wid >> 2) * 64 + part * 32 + ((wid & 3) << 3);
      int r = rb + (lane >> 3);
      int sc = scolb ^ ((r & 7) << 4);
      g2l16((const char*)(ga + (size_t)r * K) + sc, (char*)&sA[buf][0] + rb * 128);
    }
  };

  // prologue: tile 0, A-half1 newest
  stageB(0, 0);
  stageA(0, 0, 0);
  stageA(0, 0, 1);

  for (int kt = 0; kt < NK; ++kt) {
    const int cur = kt & 1;
    const bool pre = (kt + 1 < NK);

    // ---------- phase 0 ----------
    vm_wait<ABI>();
    hard_barrier();
    if (pre) stageB(kt + 1, cur ^ 1);  // STAGE first: latency hides under reads+MFMA
    bf16x8 bfr[FN][2];
#pragma unroll
    for (int fn = 0; fn < FN; ++fn) {
      int row = wn * (16 * FN) + fn * 16 + r16;
      const char* base = (const char*)&sB[cur][0] + row * 128;
      int sw = (row & 7) << 4;
#pragma unroll
      for (int kk = 0; kk < 2; ++kk)
        bfr[fn][kk] = *(const bf16x8*)(base + ((g * 16 + kk * 64) ^ sw));
    }
    bf16x8 af0[MH][2];
#pragma unroll
    for (int i = 0; i < MH; ++i) {
      int row = wm * (BM / 2) + i * 16 + r16;
      const char* base = (const char*)&sA[cur][0] + row * 128;
      int sw = (row & 7) << 4;
#pragma unroll
      for (int kk = 0; kk < 2; ++kk)
        af0[i][kk] = *(const bf16x8*)(base + ((g * 16 + kk * 64) ^ sw));
    }
    __builtin_amdgcn_s_setprio(1);
#pragma unroll
    for (int kk = 0; kk < 2; ++kk)
#pragma unroll
      for (int i = 0; i < MH; ++i)
#pragma unroll
        for (int fn = 0; fn < FN; ++fn)
          acc[i][fn] = __builtin_amdgcn_mfma_f32_16x16x32_bf16(af0[i][kk], bfr[fn][kk],
                                                               acc[i][fn], 0, 0, 0);
    __builtin_amdgcn_s_setprio(0);

    // ---------- phase 1 ----------
    if (pre) vm_wait<NBI>(); else vm_wait<0>();
    hard_barrier();
    if (pre) {
      stageA(kt + 1, cur ^ 1, 0);
      stageA(kt + 1, cur ^ 1, 1);
    }
    bf16x8 af1[MH][2];
#pragma unroll
    for (int i = 0; i < MH; ++i) {
      int row = wm * (BM / 2) + (MH + i) * 16 + r16;
      const char* base = (const char*)&sA[cur][0] + row * 128;
      int sw = (row & 7) << 4;
#pragma unroll
      for (int kk = 0; kk < 2; ++kk)
        af1[i][kk] = *(const bf16x8*)(base + ((g * 16 + kk * 64) ^ sw));
    }
    __builtin_amdgcn_s_setprio(1);
#pragma unroll
    for (int kk = 0; kk < 2; ++kk)
#pragma unroll
      for (int i = 0; i < MH; ++i)
#pragma unroll
        for (int fn = 0; fn < FN; ++fn)
          acc[MH + i][fn] = __builtin_amdgcn_mfma_f32_16x16x32_bf16(af1[i][kk], bfr[fn][kk],
                                                                    acc[MH + i][fn], 0, 0, 0);
    __builtin_amdgcn_s_setprio(0);
  }

  // ---------- epilogue ----------
#pragma unroll
  for (int fm = 0; fm < MR; ++fm)
#pragma unroll
    for (int fn = 0; fn < FN; ++fn)
#pragma unroll
      for (int j = 0; j < 4; ++j) {
        int row = m0 + wm * (BM / 2) + fm * 16 + g * 4 + j;
        int col = n0 + wn * (16 * FN) + fn * 16 + r16;
        float v = acc[fm][fn][j];
        if constexpr (sizeof(OUT) == 2)
          C[(size_t)row * N + col] = f2bf(v);
        else
          C[(size_t)row * N + col] = v;
      }
}

// ---------------- RMSNorm + RoPE + q_gain epilogue ----------------
__global__ __launch_bounds__(256) void k_normrope(const unsigned short* __restrict__ qkv,
                                                  const float* __restrict__ qg,
                                                  unsigned short* __restrict__ qn,
                                                  unsigned short* __restrict__ kn) {
  const int wid = threadIdx.x >> 6, lane = threadIdx.x & 63;
  const int b = blockIdx.x >> 7;
  const int s0 = (blockIdx.x & 127) * 16;
  const int dh = lane & 31;
  const float inv_freq = powf(10000.0f, -(float)dh * (1.0f / 32.0f));
  float sn, cs, snf, csf;
  sincosf((float)s0 * inv_freq, &sn, &cs);
  sincosf(inv_freq, &snf, &csf);  // per-step rotation
  for (int t = 0; t < 16; ++t) {
    const int s = s0 + t;
    const size_t base = (size_t)(b * 2048 + s) * 1536;
#pragma unroll
    for (int u = 0; u < 5; ++u) {
      const int unit = wid * 5 + u;  // 0..15 = q heads, 16..19 = k heads
      const int col = (unit < 16) ? unit * 64 : 1024 + (unit - 16) * 64;
      float v = bf2f(qkv[base + col + lane]);
      float ss = v * v;
      ss += __shfl_xor(ss, 1);  ss += __shfl_xor(ss, 2);  ss += __shfl_xor(ss, 4);
      ss += __shfl_xor(ss, 8);  ss += __shfl_xor(ss, 16); ss += __shfl_xor(ss, 32);
      float xr = v * rsqrtf(ss * (1.0f / 64.0f) + 1e-6f);
      float xp = __shfl_xor(xr, 32);
      float o = (lane < 32) ? (xr * cs + xp * sn) : (xr * cs - xp * sn);
      if (unit < 16) {
        o *= qg[unit] * 0.18033688011112042f;  // fold 1/8 * log2(e) into q
        qn[(size_t)(b * 2048 + s) * 1024 + unit * 64 + lane] = f2bf(o);
      } else {
        kn[(size_t)(b * 2048 + s) * 256 + (unit - 16) * 64 + lane] = f2bf(o);
      }
    }
    float cn = cs * csf - sn * snf;  // advance angle by inv_freq
    sn = sn * csf + cs * snf;
    cs = cn;
  }
}

// ---------------- V transpose: qkv v-part -> vt[b][hv][dim64][S] ----------------
__global__ __launch_bounds__(256) void k_vt(const unsigned short* __restrict__ qkv,
                                            unsigned short* __restrict__ vt) {
  __shared__ unsigned short T[64 * 64];
  const int tid = threadIdx.x;
  const int b = blockIdx.y >> 2, hv = blockIdx.y & 3;
  const int k0 = blockIdx.x * 64;
#pragma unroll
  for (int pass = 0; pass < 2; ++pass) {
    int key = pass * 32 + (tid >> 3);
    int d8 = (tid & 7) * 8;
    u16x8 v = *(const u16x8*)(qkv + (size_t)(b * 2048 + k0 + key) * 1536 + 1280 + hv * 64 + d8);
    int byte = key * 128 + ((d8 * 2) ^ ((((key & 7) ^ (key >> 3)) & 7) << 4));
    *(u16x8*)((char*)T + byte) = v;
  }
  __syncthreads();
#pragma unroll
  for (int pass = 0; pass < 2; ++pass) {
    int dim = pass * 32 + (tid >> 3);
    int k8 = (tid & 7) * 8;
    u16x8 o;
#pragma unroll
    for (int j = 0; j < 8; ++j) {
      int key = k8 + j;
      int byte = key * 128 + ((dim * 2) ^ ((((key & 7) ^ (key >> 3)) & 7) << 4));
      o[j] = *(const unsigned short*)((const char*)T + byte);
    }
    *(u16x8*)(vt + ((size_t)(b * 4 + hv) * 64 + dim) * 2048 + k0 + k8) = o;
  }
}

// ---------------- causal GQA flash attention, swapped-QK 32x32 ----------------
// grid 512: block = (pairIdx 0..7, bh); does qx=pairIdx then qx=15-pairIdx
// -> uniform ~33 wave-tiles per block (static balance).
__global__ __launch_bounds__(256) void k_attn2(const unsigned short* __restrict__ qn,
                                               const unsigned short* __restrict__ kn,
                                               const unsigned short* __restrict__ vt,
                                               unsigned short* __restrict__ yb) {
  __shared__ unsigned short SMEM[2 * 8192];  // 2 x (Ks 8KB | Vts 8KB) = 32KB
  const int tid = threadIdx.x;
  const int wid = tid >> 6, lane = tid & 63;
  const int hi = lane >> 5, l31 = lane & 31;
  const int pairIdx = blockIdx.x >> 6;
  const int bh = blockIdx.x & 63;
  const int b = bh >> 4, h = bh & 15, hv = h >> 2;
  const size_t tok0 = (size_t)b * 2048;
  const unsigned short* vtb = vt + (size_t)(b * 4 + hv) * 64 * 2048;

  auto stage = [&](int T, int buf) {
    unsigned short* KsB = SMEM + buf * 8192;
    unsigned short* VtB = KsB + 4096;
    const int kk0 = T * 64;
#pragma unroll
    for (int c = 0; c < 2; ++c) {
      int i = wid * 2 + c;
      int row = i * 8 + (lane >> 3);
      int sc = ((lane & 7) * 16) ^ ((row & 7) << 4);
      g2l16((const char*)(kn + (tok0 + kk0 + row) * 256 + hv * 64) + sc, (char*)KsB + i * 1024);
      g2l16((const char*)(vtb + (size_t)row * 2048 + kk0) + sc, (char*)VtB + i * 1024);
    }
  };

  for (int pass = 0; pass < 2; ++pass) {
    const int qx = pass ? (15 - pairIdx) : pairIdx;
    const int q0w = qx * 128 + wid * 32;
    const int qglob = q0w + l31;

    bf16x8 qf[4];
#pragma unroll
    for (int m = 0; m < 4; ++m)
      qf[m] = *(const bf16x8*)(qn + (tok0 + qglob) * 1024 + h * 64 + m * 16 + hi * 8);

    f32x16 oacc[2];
#pragma unroll
    for (int db = 0; db < 2; ++db)
#pragma unroll
      for (int r = 0; r < 16; ++r) oacc[db][r] = 0.f;
    float mrun = -INFINITY, lrun = 0.f;

    const int nt = qx * 2 + 2;

    stage(0, 0);
    __syncthreads();

    int cur = 0;
    for (int t = 0; t < nt; ++t) {
      const int k0 = t * 64;
      if (t + 1 < nt) stage(t + 1, cur ^ 1);  // prefetch overlaps compute below

      if (k0 <= q0w + 31) {
        const unsigned short* KsB = SMEM + cur * 8192;
        const unsigned short* VtB = KsB + 4096;
        // ---- S^T[key][q] = K · Q^T ----
        f32x16 s[2];
#pragma unroll
        for (int kt = 0; kt < 2; ++kt) {
          f32x16 acc;
#pragma unroll
          for (int r = 0; r < 16; ++r) acc[r] = 0.f;
          const int krow = kt * 32 + l31;
          const char* kbase = (const char*)KsB + krow * 128;
          const int ksw = (krow & 7) << 4;
          __builtin_amdgcn_s_setprio(1);
#pragma unroll
          for (int m = 0; m < 4; ++m) {
            bf16x8 kf = *(const bf16x8*)(kbase + ((m * 32 + hi * 16) ^ ksw));
            acc = __builtin_amdgcn_mfma_f32_32x32x16_bf16(kf, qf[m], acc, 0, 0, 0);
          }
          __builtin_amdgcn_s_setprio(0);
          s[kt] = acc;
        }
        // ---- causal mask (near-diagonal tiles only) ----
        if (k0 + 63 > q0w) {
#pragma unroll
          for (int kt = 0; kt < 2; ++kt)
#pragma unroll
            for (int r = 0; r < 16; ++r) {
              int key = k0 + kt * 32 + (r & 3) + 8 * (r >> 2) + 4 * hi;
              if (key > qglob) s[kt][r] = -INFINITY;
            }
        }
        // ---- online softmax, per-lane scalar state, log2 domain, defer-max ----
        float red[16];
#pragma unroll
        for (int r = 0; r < 16; ++r) red[r] = fmaxf(s[0][r], s[1][r]);
#pragma unroll
        for (int r = 0; r < 8; ++r) red[r] = fmaxf(red[r], red[r + 8]);
#pragma unroll
        for (int r = 0; r < 4; ++r) red[r] = fmaxf(red[r], red[r + 4]);
        float mx = fmaxf(fmaxf(red[0], red[1]), fmaxf(red[2], red[3]));
        mx = fmaxf(mx, __shfl_xor(mx, 32));
        if (!__all(mx - mrun <= 8.0f)) {
          float mnew = fmaxf(mrun, mx);
          float fsc = exp2f(mrun - mnew);
          lrun *= fsc;
#pragma unroll
          for (int db = 0; db < 2; ++db)
#pragma unroll
            for (int r = 0; r < 16; ++r) oacc[db][r] *= fsc;
          mrun = mnew;
        }
#pragma unroll
        for (int kt = 0; kt < 2; ++kt)
#pragma unroll
          for (int r = 0; r < 16; ++r) s[kt][r] = exp2f(s[kt][r] - mrun);
        float sr[16];
#pragma unroll
        for (int r = 0; r < 16; ++r) sr[r] = s[0][r] + s[1][r];
#pragma unroll
        for (int r = 0; r < 8; ++r) sr[r] += sr[r + 8];
#pragma unroll
        for (int r = 0; r < 4; ++r) sr[r] += sr[r + 4];
        float ps = (sr[0] + sr[1]) + (sr[2] + sr[3]);
        ps += __shfl_xor(ps, 32);
        lrun += ps;
        // ---- P -> bf16 frags via cvt_pk + permlane32_swap (T12) ----
        i32x4 paw[4];
#pragma unroll
        for (int kt = 0; kt < 2; ++kt)
#pragma unroll
          for (int half = 0; half < 2; ++half) {
            int bs = half * 8;
            unsigned int a0 = cvtpk(s[kt][bs + 0], s[kt][bs + 1]);
            unsigned int a1 = cvtpk(s[kt][bs + 2], s[kt][bs + 3]);
            unsigned int b0 = cvtpk(s[kt][bs + 4], s[kt][bs + 5]);
            unsigned int b1 = cvtpk(s[kt][bs + 6], s[kt][bs + 7]);
            i32x2 r0 = __builtin_amdgcn_permlane32_swap((int)a0, (int)b0, false, false);
            i32x2 r1 = __builtin_amdgcn_permlane32_swap((int)a1, (int)b1, false, false);
            i32x4 w;
            w[0] = r0[0]; w[1] = r1[0]; w[2] = r0[1]; w[3] = r1[1];
            paw[kt * 2 + half] = w;
          }
        // ---- O^T += V^T · P^T ----
#pragma unroll
        for (int db = 0; db < 2; ++db) {
          const int vrow = db * 32 + l31;
          const char* vbase = (const char*)VtB + vrow * 128;
          const int vsw = (vrow & 7) << 4;
          __builtin_amdgcn_s_setprio(1);
#pragma unroll
          for (int ks = 0; ks < 4; ++ks) {
            bf16x8 vf = *(const bf16x8*)(vbase + ((ks * 32 + hi * 16) ^ vsw));
            oacc[db] = __builtin_amdgcn_mfma_f32_32x32x16_bf16(
                vf, __builtin_bit_cast(bf16x8, paw[ks]), oacc[db], 0, 0, 0);
          }
          __builtin_amdgcn_s_setprio(0);
        }
      }
      __syncthreads();  // drains prefetch + protects buffer swap
      cur ^= 1;
    }

    // ---- epilogue: O^T -> per-wave LDS transpose -> coalesced row store ----
    const float inv = 1.0f / lrun;
    const int swl = (l31 & 7) << 4;
    char* obase = (char*)SMEM + wid * 4096;
#pragma unroll
    for (int db = 0; db < 2; ++db)
#pragma unroll
      for (int i = 0; i < 8; ++i) {
        int r = 2 * i;
        int dim = db * 32 + (r & 3) + 8 * (r >> 2) + 4 * hi;
        unsigned int w = (unsigned int)f2bf(oacc[db][r] * inv) |
                         ((unsigned int)f2bf(oacc[db][r + 1] * inv) << 16);
        *(unsigned int*)(obase + l31 * 128 + ((dim * 2) ^ swl)) = w;
      }
    __syncthreads();
#pragma unroll
    for (int it = 0; it < 4; ++it) {
      int cc = it * 2 + hi;
      i32x4 w = *(const i32x4*)(obase + l31 * 128 + ((cc * 16) ^ swl));
      *(i32x4*)(yb + (tok0 + q0w + l31) * 1024 + h * 64 + cc * 8) = w;
    }
    __syncthreads();  // SMEM reused by next pass staging
  }
}

// ---------------- launch ----------------
extern "C" void kernel_launch(void* const* d_in, const int* in_sizes, int n_in,
                              void* d_out, int out_size, void* d_ws, size_t ws_size,
                              hipStream_t stream) {
  (void)in_sizes; (void)n_in; (void)out_size; (void)ws_size;
  const float* x  = (const float*)d_in[0];
  const float* Wq = (const float*)d_in[1];
  const float* Wk = (const float*)d_in[2];
  const float* Wv = (const float*)d_in[3];
  const float* Wo = (const float*)d_in[4];
  const float* qg = (const float*)d_in[5];

  char* ws = (char*)d_ws;
  unsigned short* xb   = (unsigned short*)(ws);             // 16 MB  [8192][1024]
  unsigned short* wcat = (unsigned short*)(ws + 16777216);  // 3 MB   [1536][1024]
  unsigned short* wob  = (unsigned short*)(ws + 19922944);  // 2 MB   [1024][1024]
  unsigned short* qn   = (unsigned short*)(ws + 22020096);  // 16 MB  [8192][1024]
  unsigned short* kn   = (unsigned short*)(ws + 38797312);  // 4 MB   [8192][256]
  unsigned short* yb   = xb;                                // alias: xb dead after QKV GEMM
  unsigned short* qkv  = (unsigned short*)d_out;            // 24 MB scratch in d_out
  unsigned short* vt   = (unsigned short*)((char*)d_out + 25165824);  // 4 MB [16][64][2048]

  k_cvt<<<4096, 256, 0, stream>>>(x, xb, 8388608);
  k_cvt<<<512, 256, 0, stream>>>(Wq, wcat, 1048576);
  k_cvt<<<128, 256, 0, stream>>>(Wk, wcat + 1048576, 262144);
  k_cvt<<<128, 256, 0, stream>>>(Wv, wcat + 1310720, 262144);
  k_cvt<<<512, 256, 0, stream>>>(Wo, wob, 1048576);

  k_gemm8<256, 192, unsigned short><<<dim3(32, 8), 512, 0, stream>>>(xb, wcat, qkv, 8192, 1536, 1024);
  k_normrope<<<512, 256, 0, stream>>>(qkv, qg, qn, kn);
  k_vt<<<dim3(32, 16), 256, 0, stream>>>(qkv, vt);
  k_attn2<<<512, 256, 0, stream>>>(qn, kn, vt, yb);
  k_gemm8<128, 256, float><<<dim3(64, 4), 512, 0, stream>>>(yb, wob, (float*)d_out, 8192, 1024, 1024);
}

// Round 6
// 233.333 us; speedup vs baseline: 1.0001x; 1.0001x over previous
//
#include <hip/hip_runtime.h>

typedef float f32x4 __attribute__((ext_vector_type(4)));
typedef float f32x16 __attribute__((ext_vector_type(16)));
typedef __bf16 bf16x8 __attribute__((ext_vector_type(8)));
typedef unsigned short u16x8 __attribute__((ext_vector_type(8)));
typedef int i32x2 __attribute__((ext_vector_type(2)));
typedef int i32x4 __attribute__((ext_vector_type(4)));

#define DEV static __device__ __forceinline__

DEV float bf2f(unsigned short h) {
  unsigned int u = ((unsigned int)h) << 16;
  return __builtin_bit_cast(float, u);
}
DEV unsigned short f2bf(float f) {
  unsigned int u = __builtin_bit_cast(unsigned int, f);
  u += 0x7fff + ((u >> 16) & 1);   // RTNE
  return (unsigned short)(u >> 16);
}

DEV void g2l16(const void* g, void* l) {
  __builtin_amdgcn_global_load_lds(
      (const __attribute__((address_space(1))) void*)g,
      (__attribute__((address_space(3))) void*)l, 16, 0, 0);
}

template <int N> DEV void vm_wait() {
  asm volatile("s_waitcnt vmcnt(%0)" ::"n"(N) : "memory");
}
DEV void hard_barrier() {
  __builtin_amdgcn_s_barrier();
  __builtin_amdgcn_sched_barrier(0);  // pin: nothing crosses the barrier
}

DEV unsigned int cvtpk(float lo, float hi) {
  unsigned int r;
  asm("v_cvt_pk_bf16_f32 %0, %1, %2" : "=v"(r) : "v"(lo), "v"(hi));
  return r;
}

// ---------------- fp32 -> bf16 convert (n % 8 == 0) ----------------
__global__ __launch_bounds__(256) void k_cvt(const float* __restrict__ in,
                                             unsigned short* __restrict__ out, int n) {
  int i = (blockIdx.x * 256 + threadIdx.x) * 8;
  if (i >= n) return;
  float4 a = *(const float4*)(in + i);
  float4 b = *(const float4*)(in + i + 4);
  u16x8 r;
  r[0] = f2bf(a.x); r[1] = f2bf(a.y); r[2] = f2bf(a.z); r[3] = f2bf(a.w);
  r[4] = f2bf(b.x); r[5] = f2bf(b.y); r[6] = f2bf(b.z); r[7] = f2bf(b.w);
  *(u16x8*)(out + i) = r;
}

// ---------------- NT GEMM, counted-vmcnt 2-phase pipeline ----------------
// C[M,N] = A[M,K] * B[N,K]^T. 512 threads (8 waves: 2m x 4n), BK=64.
// Ledger (issues of 8KB each): stageB = NBI, stageA half = ABI.
// phase0(t): wait vmcnt(ABI)  [A1(t) in flight]; stage B(t+1); read B(t),A0(t)
// phase1(t): wait vmcnt(NBI)  [B(t+1) in flight]; stage A(t+1); read A1(t)
template <int BM, int BN, typename OUT>
__global__ __launch_bounds__(512, 1) void k_gemm8(const unsigned short* __restrict__ A,
                                                  const unsigned short* __restrict__ B,
                                                  OUT* __restrict__ C, int M, int N, int K) {
  constexpr int MR = BM / 32;       // per-wave m-frags
  constexpr int MH = MR / 2;        // m-frags per phase
  constexpr int FN = BN >> 6;       // per-wave n-frags
  constexpr int NBI = (BN * 128) / 8192;       // B issues per tile
  constexpr int ABI = (BM * 128) / 8192 / 2;   // A issues per half-tile
  __shared__ unsigned short sA[2][BM * 64];
  __shared__ unsigned short sB[2][BN * 64];
  const int tid = threadIdx.x;
  const int wid = tid >> 6, lane = tid & 63;
  const int wm = wid >> 2, wn = wid & 3;
  const int g = lane >> 4, r16 = lane & 15;
  const int m0 = blockIdx.x * BM, n0 = blockIdx.y * BN;
  const int NK = K >> 6;

  const int srow = (wid << 3) + (lane >> 3);
  const int scolb = (lane & 7) << 4;

  f32x4 acc[MR][FN];
#pragma unroll
  for (int i = 0; i < MR; ++i)
#pragma unroll
    for (int j = 0; j < FN; ++j) acc[i][j] = f32x4{0.f, 0.f, 0.f, 0.f};

  auto stageB = [&](int kt, int buf) {
    const unsigned short* gb = B + (size_t)n0 * K + (kt << 6);
#pragma unroll
    for (int c = 0; c < NBI; ++c) {
      int r = c * 64 + srow;
      int sc = scolb ^ ((r & 7) << 4);
      g2l16((const char*)(gb + (size_t)r * K) + sc, (char*)&sB[buf][0] + c * 8192 + wid * 1024);
    }
  };
  auto stageA = [&](int kt, int buf, int part) {
    const unsigned short* ga = A + (size_t)m0 * K + (kt << 6);
    if constexpr (BM == 256) {
#pragma unroll
      for (int c = 0; c < 2; ++c) {
        int r = c * 128 + part * 64 + srow;
        int sc = scolb ^ ((r & 7) << 4);
        g2l16((const char*)(ga + (size_t)r * K) + sc,
              (char*)&sA[buf][0] + c * 16384 + part * 8192 + wid * 1024);
      }
    } else {
      int rb = (wid >> 2) * 64 + part * 32 + ((wid & 3) << 3);
      int r = rb + (lane >> 3);
      int sc = scolb ^ ((r & 7) << 4);
      g2l16((const char*)(ga + (size_t)r * K) + sc, (char*)&sA[buf][0] + rb * 128);
    }
  };

  // prologue: tile 0, A-half1 newest
  stageB(0, 0);
  stageA(0, 0, 0);
  stageA(0, 0, 1);

  for (int kt = 0; kt < NK; ++kt) {
    const int cur = kt & 1;
    const bool pre = (kt + 1 < NK);

    // ---------- phase 0 ----------
    vm_wait<ABI>();
    hard_barrier();
    if (pre) stageB(kt + 1, cur ^ 1);  // STAGE first: latency hides under reads+MFMA
    bf16x8 bfr[FN][2];
#pragma unroll
    for (int fn = 0; fn < FN; ++fn) {
      int row = wn * (16 * FN) + fn * 16 + r16;
      const char* base = (const char*)&sB[cur][0] + row * 128;
      int sw = (row & 7) << 4;
#pragma unroll
      for (int kk = 0; kk < 2; ++kk)
        bfr[fn][kk] = *(const bf16x8*)(base + ((g * 16 + kk * 64) ^ sw));
    }
    bf16x8 af0[MH][2];
#pragma unroll
    for (int i = 0; i < MH; ++i) {
      int row = wm * (BM / 2) + i * 16 + r16;
      const char* base = (const char*)&sA[cur][0] + row * 128;
      int sw = (row & 7) << 4;
#pragma unroll
      for (int kk = 0; kk < 2; ++kk)
        af0[i][kk] = *(const bf16x8*)(base + ((g * 16 + kk * 64) ^ sw));
    }
    __builtin_amdgcn_s_setprio(1);
#pragma unroll
    for (int kk = 0; kk < 2; ++kk)
#pragma unroll
      for (int i = 0; i < MH; ++i)
#pragma unroll
        for (int fn = 0; fn < FN; ++fn)
          acc[i][fn] = __builtin_amdgcn_mfma_f32_16x16x32_bf16(af0[i][kk], bfr[fn][kk],
                                                               acc[i][fn], 0, 0, 0);
    __builtin_amdgcn_s_setprio(0);

    // ---------- phase 1 ----------
    if (pre) vm_wait<NBI>(); else vm_wait<0>();
    hard_barrier();
    if (pre) {
      stageA(kt + 1, cur ^ 1, 0);
      stageA(kt + 1, cur ^ 1, 1);
    }
    bf16x8 af1[MH][2];
#pragma unroll
    for (int i = 0; i < MH; ++i) {
      int row = wm * (BM / 2) + (MH + i) * 16 + r16;
      const char* base = (const char*)&sA[cur][0] + row * 128;
      int sw = (row & 7) << 4;
#pragma unroll
      for (int kk = 0; kk < 2; ++kk)
        af1[i][kk] = *(const bf16x8*)(base + ((g * 16 + kk * 64) ^ sw));
    }
    __builtin_amdgcn_s_setprio(1);
#pragma unroll
    for (int kk = 0; kk < 2; ++kk)
#pragma unroll
      for (int i = 0; i < MH; ++i)
#pragma unroll
        for (int fn = 0; fn < FN; ++fn)
          acc[MH + i][fn] = __builtin_amdgcn_mfma_f32_16x16x32_bf16(af1[i][kk], bfr[fn][kk],
                                                                    acc[MH + i][fn], 0, 0, 0);
    __builtin_amdgcn_s_setprio(0);
  }

  // ---------- epilogue ----------
#pragma unroll
  for (int fm = 0; fm < MR; ++fm)
#pragma unroll
    for (int fn = 0; fn < FN; ++fn)
#pragma unroll
      for (int j = 0; j < 4; ++j) {
        int row = m0 + wm * (BM / 2) + fm * 16 + g * 4 + j;
        int col = n0 + wn * (16 * FN) + fn * 16 + r16;
        float v = acc[fm][fn][j];
        if constexpr (sizeof(OUT) == 2)
          C[(size_t)row * N + col] = f2bf(v);
        else
          C[(size_t)row * N + col] = v;
      }
}

// ---------------- RMSNorm + RoPE + q_gain epilogue ----------------
__global__ __launch_bounds__(256) void k_normrope(const unsigned short* __restrict__ qkv,
                                                  const float* __restrict__ qg,
                                                  unsigned short* __restrict__ qn,
                                                  unsigned short* __restrict__ kn) {
  const int wid = threadIdx.x >> 6, lane = threadIdx.x & 63;
  const int b = blockIdx.x >> 7;
  const int s0 = (blockIdx.x & 127) * 16;
  const int dh = lane & 31;
  const float inv_freq = powf(10000.0f, -(float)dh * (1.0f / 32.0f));
  float sn, cs, snf, csf;
  sincosf((float)s0 * inv_freq, &sn, &cs);
  sincosf(inv_freq, &snf, &csf);  // per-step rotation
  for (int t = 0; t < 16; ++t) {
    const int s = s0 + t;
    const size_t base = (size_t)(b * 2048 + s) * 1536;
#pragma unroll
    for (int u = 0; u < 5; ++u) {
      const int unit = wid * 5 + u;  // 0..15 = q heads, 16..19 = k heads
      const int col = (unit < 16) ? unit * 64 : 1024 + (unit - 16) * 64;
      float v = bf2f(qkv[base + col + lane]);
      float ss = v * v;
      ss += __shfl_xor(ss, 1);  ss += __shfl_xor(ss, 2);  ss += __shfl_xor(ss, 4);
      ss += __shfl_xor(ss, 8);  ss += __shfl_xor(ss, 16); ss += __shfl_xor(ss, 32);
      float xr = v * rsqrtf(ss * (1.0f / 64.0f) + 1e-6f);
      float xp = __shfl_xor(xr, 32);
      float o = (lane < 32) ? (xr * cs + xp * sn) : (xr * cs - xp * sn);
      if (unit < 16) {
        o *= qg[unit] * 0.18033688011112042f;  // fold 1/8 * log2(e) into q
        qn[(size_t)(b * 2048 + s) * 1024 + unit * 64 + lane] = f2bf(o);
      } else {
        kn[(size_t)(b * 2048 + s) * 256 + (unit - 16) * 64 + lane] = f2bf(o);
      }
    }
    float cn = cs * csf - sn * snf;  // advance angle by inv_freq
    sn = sn * csf + cs * snf;
    cs = cn;
  }
}

// ---------------- V transpose: qkv v-part -> vt[b][hv][dim64][S] ----------------
__global__ __launch_bounds__(256) void k_vt(const unsigned short* __restrict__ qkv,
                                            unsigned short* __restrict__ vt) {
  __shared__ unsigned short T[64 * 64];
  const int tid = threadIdx.x;
  const int b = blockIdx.y >> 2, hv = blockIdx.y & 3;
  const int k0 = blockIdx.x * 64;
#pragma unroll
  for (int pass = 0; pass < 2; ++pass) {
    int key = pass * 32 + (tid >> 3);
    int d8 = (tid & 7) * 8;
    u16x8 v = *(const u16x8*)(qkv + (size_t)(b * 2048 + k0 + key) * 1536 + 1280 + hv * 64 + d8);
    int byte = key * 128 + ((d8 * 2) ^ ((((key & 7) ^ (key >> 3)) & 7) << 4));
    *(u16x8*)((char*)T + byte) = v;
  }
  __syncthreads();
#pragma unroll
  for (int pass = 0; pass < 2; ++pass) {
    int dim = pass * 32 + (tid >> 3);
    int k8 = (tid & 7) * 8;
    u16x8 o;
#pragma unroll
    for (int j = 0; j < 8; ++j) {
      int key = k8 + j;
      int byte = key * 128 + ((dim * 2) ^ ((((key & 7) ^ (key >> 3)) & 7) << 4));
      o[j] = *(const unsigned short*)((const char*)T + byte);
    }
    *(u16x8*)(vt + ((size_t)(b * 4 + hv) * 64 + dim) * 2048 + k0 + k8) = o;
  }
}

// ---------------- causal GQA flash attention, swapped-QK 32x32 ----------------
// grid 512: block = (pairIdx 0..7, bh); does qx=pairIdx then qx=15-pairIdx
// -> uniform ~33 wave-tiles per block (static balance).
__global__ __launch_bounds__(256) void k_attn2(const unsigned short* __restrict__ qn,
                                               const unsigned short* __restrict__ kn,
                                               const unsigned short* __restrict__ vt,
                                               unsigned short* __restrict__ yb) {
  __shared__ unsigned short SMEM[2 * 8192];  // 2 x (Ks 8KB | Vts 8KB) = 32KB
  const int tid = threadIdx.x;
  const int wid = tid >> 6, lane = tid & 63;
  const int hi = lane >> 5, l31 = lane & 31;
  const int pairIdx = blockIdx.x >> 6;
  const int bh = blockIdx.x & 63;
  const int b = bh >> 4, h = bh & 15, hv = h >> 2;
  const size_t tok0 = (size_t)b * 2048;
  const unsigned short* vtb = vt + (size_t)(b * 4 + hv) * 64 * 2048;

  auto stage = [&](int T, int buf) {
    unsigned short* KsB = SMEM + buf * 8192;
    unsigned short* VtB = KsB + 4096;
    const int kk0 = T * 64;
#pragma unroll
    for (int c = 0; c < 2; ++c) {
      int i = wid * 2 + c;
      int row = i * 8 + (lane >> 3);
      int sc = ((lane & 7) * 16) ^ ((row & 7) << 4);
      g2l16((const char*)(kn + (tok0 + kk0 + row) * 256 + hv * 64) + sc, (char*)KsB + i * 1024);
      g2l16((const char*)(vtb + (size_t)row * 2048 + kk0) + sc, (char*)VtB + i * 1024);
    }
  };

  for (int pass = 0; pass < 2; ++pass) {
    const int qx = pass ? (15 - pairIdx) : pairIdx;
    const int q0w = qx * 128 + wid * 32;
    const int qglob = q0w + l31;

    bf16x8 qf[4];
#pragma unroll
    for (int m = 0; m < 4; ++m)
      qf[m] = *(const bf16x8*)(qn + (tok0 + qglob) * 1024 + h * 64 + m * 16 + hi * 8);

    f32x16 oacc[2];
#pragma unroll
    for (int db = 0; db < 2; ++db)
#pragma unroll
      for (int r = 0; r < 16; ++r) oacc[db][r] = 0.f;
    float mrun = -INFINITY, lrun = 0.f;

    const int nt = qx * 2 + 2;

    stage(0, 0);
    __syncthreads();

    int cur = 0;
    for (int t = 0; t < nt; ++t) {
      const int k0 = t * 64;
      if (t + 1 < nt) stage(t + 1, cur ^ 1);  // prefetch overlaps compute below

      if (k0 <= q0w + 31) {
        const unsigned short* KsB = SMEM + cur * 8192;
        const unsigned short* VtB = KsB + 4096;
        // ---- S^T[key][q] = K · Q^T ----
        f32x16 s[2];
#pragma unroll
        for (int kt = 0; kt < 2; ++kt) {
          f32x16 acc;
#pragma unroll
          for (int r = 0; r < 16; ++r) acc[r] = 0.f;
          const int krow = kt * 32 + l31;
          const char* kbase = (const char*)KsB + krow * 128;
          const int ksw = (krow & 7) << 4;
          __builtin_amdgcn_s_setprio(1);
#pragma unroll
          for (int m = 0; m < 4; ++m) {
            bf16x8 kf = *(const bf16x8*)(kbase + ((m * 32 + hi * 16) ^ ksw));
            acc = __builtin_amdgcn_mfma_f32_32x32x16_bf16(kf, qf[m], acc, 0, 0, 0);
          }
          __builtin_amdgcn_s_setprio(0);
          s[kt] = acc;
        }
        // ---- causal mask (near-diagonal tiles only) ----
        if (k0 + 63 > q0w) {
#pragma unroll
          for (int kt = 0; kt < 2; ++kt)
#pragma unroll
            for (int r = 0; r < 16; ++r) {
              int key = k0 + kt * 32 + (r & 3) + 8 * (r >> 2) + 4 * hi;
              if (key > qglob) s[kt][r] = -INFINITY;
            }
        }
        // ---- online softmax, per-lane scalar state, log2 domain, defer-max ----
        float red[16];
#pragma unroll
        for (int r = 0; r < 16; ++r) red[r] = fmaxf(s[0][r], s[1][r]);
#pragma unroll
        for (int r = 0; r < 8; ++r) red[r] = fmaxf(red[r], red[r + 8]);
#pragma unroll
        for (int r = 0; r < 4; ++r) red[r] = fmaxf(red[r], red[r + 4]);
        float mx = fmaxf(fmaxf(red[0], red[1]), fmaxf(red[2], red[3]));
        mx = fmaxf(mx, __shfl_xor(mx, 32));
        if (!__all(mx - mrun <= 8.0f)) {
          float mnew = fmaxf(mrun, mx);
          float fsc = exp2f(mrun - mnew);
          lrun *= fsc;
#pragma unroll
          for (int db = 0; db < 2; ++db)
#pragma unroll
            for (int r = 0; r < 16; ++r) oacc[db][r] *= fsc;
          mrun = mnew;
        }
#pragma unroll
        for (int kt = 0; kt < 2; ++kt)
#pragma unroll
          for (int r = 0; r < 16; ++r) s[kt][r] = exp2f(s[kt][r] - mrun);
        float sr[16];
#pragma unroll
        for (int r = 0; r < 16; ++r) sr[r] = s[0][r] + s[1][r];
#pragma unroll
        for (int r = 0; r < 8; ++r) sr[r] += sr[r + 8];
#pragma unroll
        for (int r = 0; r < 4; ++r) sr[r] += sr[r + 4];
        float ps = (sr[0] + sr[1]) + (sr[2] + sr[3]);
        ps += __shfl_xor(ps, 32);
        lrun += ps;
        // ---- P -> bf16 frags via cvt_pk + permlane32_swap (T12) ----
        i32x4 paw[4];
#pragma unroll
        for (int kt = 0; kt < 2; ++kt)
#pragma unroll
          for (int half = 0; half < 2; ++half) {
            int bs = half * 8;
            unsigned int a0 = cvtpk(s[kt][bs + 0], s[kt][bs + 1]);
            unsigned int a1 = cvtpk(s[kt][bs + 2], s[kt][bs + 3]);
            unsigned int b0 = cvtpk(s[kt][bs + 4], s[kt][bs + 5]);
            unsigned int b1 = cvtpk(s[kt][bs + 6], s[kt][bs + 7]);
            i32x2 r0 = __builtin_amdgcn_permlane32_swap((int)a0, (int)b0, false, false);
            i32x2 r1 = __builtin_amdgcn_permlane32_swap((int)a1, (int)b1, false, false);
            i32x4 w;
            w[0] = r0[0]; w[1] = r1[0]; w[2] = r0[1]; w[3] = r1[1];
            paw[kt * 2 + half] = w;
          }
        // ---- O^T += V^T · P^T ----
#pragma unroll
        for (int db = 0; db < 2; ++db) {
          const int vrow = db * 32 + l31;
          const char* vbase = (const char*)VtB + vrow * 128;
          const int vsw = (vrow & 7) << 4;
          __builtin_amdgcn_s_setprio(1);
#pragma unroll
          for (int ks = 0; ks < 4; ++ks) {
            bf16x8 vf = *(const bf16x8*)(vbase + ((ks * 32 + hi * 16) ^ vsw));
            oacc[db] = __builtin_amdgcn_mfma_f32_32x32x16_bf16(
                vf, __builtin_bit_cast(bf16x8, paw[ks]), oacc[db], 0, 0, 0);
          }
          __builtin_amdgcn_s_setprio(0);
        }
      }
      __syncthreads();  // drains prefetch + protects buffer swap
      cur ^= 1;
    }

    // ---- epilogue: O^T -> per-wave LDS transpose -> coalesced row store ----
    const float inv = 1.0f / lrun;
    const int swl = (l31 & 7) << 4;
    char* obase = (char*)SMEM + wid * 4096;
#pragma unroll
    for (int db = 0; db < 2; ++db)
#pragma unroll
      for (int i = 0; i < 8; ++i) {
        int r = 2 * i;
        int dim = db * 32 + (r & 3) + 8 * (r >> 2) + 4 * hi;
        unsigned int w = (unsigned int)f2bf(oacc[db][r] * inv) |
                         ((unsigned int)f2bf(oacc[db][r + 1] * inv) << 16);
        *(unsigned int*)(obase + l31 * 128 + ((dim * 2) ^ swl)) = w;
      }
    __syncthreads();
#pragma unroll
    for (int it = 0; it < 4; ++it) {
      int cc = it * 2 + hi;
      i32x4 w = *(const i32x4*)(obase + l31 * 128 + ((cc * 16) ^ swl));
      *(i32x4*)(yb + (tok0 + q0w + l31) * 1024 + h * 64 + cc * 8) = w;
    }
    __syncthreads();  // SMEM reused by next pass staging
  }
}

// ---------------- launch ----------------
extern "C" void kernel_launch(void* const* d_in, const int* in_sizes, int n_in,
                              void* d_out, int out_size, void* d_ws, size_t ws_size,
                              hipStream_t stream) {
  (void)in_sizes; (void)n_in; (void)out_size; (void)ws_size;
  const float* x  = (const float*)d_in[0];
  const float* Wq = (const float*)d_in[1];
  const float* Wk = (const float*)d_in[2];
  const float* Wv = (const float*)d_in[3];
  const float* Wo = (const float*)d_in[4];
  const float* qg = (const float*)d_in[5];

  char* ws = (char*)d_ws;
  unsigned short* xb   = (unsigned short*)(ws);             // 16 MB  [8192][1024]
  unsigned short* wcat = (unsigned short*)(ws + 16777216);  // 3 MB   [1536][1024]
  unsigned short* wob  = (unsigned short*)(ws + 19922944);  // 2 MB   [1024][1024]
  unsigned short* qn   = (unsigned short*)(ws + 22020096);  // 16 MB  [8192][1024]
  unsigned short* kn   = (unsigned short*)(ws + 38797312);  // 4 MB   [8192][256]
  unsigned short* yb   = xb;                                // alias: xb dead after QKV GEMM
  unsigned short* qkv  = (unsigned short*)d_out;            // 24 MB scratch in d_out
  unsigned short* vt   = (unsigned short*)((char*)d_out + 25165824);  // 4 MB [16][64][2048]

  k_cvt<<<4096, 256, 0, stream>>>(x, xb, 8388608);
  k_cvt<<<512, 256, 0, stream>>>(Wq, wcat, 1048576);
  k_cvt<<<128, 256, 0, stream>>>(Wk, wcat + 1048576, 262144);
  k_cvt<<<128, 256, 0, stream>>>(Wv, wcat + 1310720, 262144);
  k_cvt<<<512, 256, 0, stream>>>(Wo, wob, 1048576);

  k_gemm8<256, 192, unsigned short><<<dim3(32, 8), 512, 0, stream>>>(xb, wcat, qkv, 8192, 1536, 1024);
  k_normrope<<<512, 256, 0, stream>>>(qkv, qg, qn, kn);
  k_vt<<<dim3(32, 16), 256, 0, stream>>>(qkv, vt);
  k_attn2<<<512, 256, 0, stream>>>(qn, kn, vt, yb);
  k_gemm8<128, 256, float><<<dim3(64, 4), 512, 0, stream>>>(yb, wob, (float*)d_out, 8192, 1024, 1024);
}

// Round 7
// 219.235 us; speedup vs baseline: 1.0644x; 1.0643x over previous
//
#include <hip/hip_runtime.h>

typedef float f32x4 __attribute__((ext_vector_type(4)));
typedef float f32x16 __attribute__((ext_vector_type(16)));
typedef __bf16 bf16x8 __attribute__((ext_vector_type(8)));
typedef unsigned short u16x8 __attribute__((ext_vector_type(8)));
typedef int i32x2 __attribute__((ext_vector_type(2)));
typedef int i32x4 __attribute__((ext_vector_type(4)));

#define DEV static __device__ __forceinline__

DEV float bf2f(unsigned short h) {
  unsigned int u = ((unsigned int)h) << 16;
  return __builtin_bit_cast(float, u);
}
DEV unsigned short f2bf(float f) {
  unsigned int u = __builtin_bit_cast(unsigned int, f);
  u += 0x7fff + ((u >> 16) & 1);   // RTNE
  return (unsigned short)(u >> 16);
}

DEV void g2l16(const void* g, void* l) {
  __builtin_amdgcn_global_load_lds(
      (const __attribute__((address_space(1))) void*)g,
      (__attribute__((address_space(3))) void*)l, 16, 0, 0);
}

DEV unsigned int cvtpk(float lo, float hi) {
  unsigned int r;
  asm("v_cvt_pk_bf16_f32 %0, %1, %2" : "=v"(r) : "v"(lo), "v"(hi));
  return r;
}

// ---------------- fp32 -> bf16 convert (n % 8 == 0) ----------------
__global__ __launch_bounds__(256) void k_cvt(const float* __restrict__ in,
                                             unsigned short* __restrict__ out, int n) {
  int i = (blockIdx.x * 256 + threadIdx.x) * 8;
  if (i >= n) return;
  float4 a = *(const float4*)(in + i);
  float4 b = *(const float4*)(in + i + 4);
  u16x8 r;
  r[0] = f2bf(a.x); r[1] = f2bf(a.y); r[2] = f2bf(a.z); r[3] = f2bf(a.w);
  r[4] = f2bf(b.x); r[5] = f2bf(b.y); r[6] = f2bf(b.z); r[7] = f2bf(b.w);
  *(u16x8*)(out + i) = r;
}

// ---------------- NT GEMM: C[M,N] = A[M,K] * B[N,K]^T  (m97 structure + T1 XCD panels) ----
// 128x128 tile, BK=64, 4 waves (2x2). 1D grid; block mapping:
//   xcd = bid & 7, local = bid >> 3; n-outer/m-inner within the XCD, so each
//   XCD keeps a 1024-row A-chunk (2MB) L2-resident and consecutive blocks
//   share one 256KB B-panel.  MT must be 64 (M=8192).
template <typename OUT>
__global__ __launch_bounds__(256) void k_gemm_bt(const unsigned short* __restrict__ A,
                                                 const unsigned short* __restrict__ B,
                                                 OUT* __restrict__ C, int M, int N, int K) {
  __shared__ unsigned short As[128 * 64];
  __shared__ unsigned short Bs[128 * 64];
  const int tid = threadIdx.x;
  const int wid = tid >> 6, lane = tid & 63;
  const int g = lane >> 4, r16 = lane & 15;
  const int xcd = blockIdx.x & 7, local = blockIdx.x >> 3;
  const int m0 = (xcd * 8 + (local & 7)) * 128;   // 8 m-tiles per XCD (MCHUNK=8)
  const int n0 = (local >> 3) * 128;              // n-outer
  const int wr = wid >> 1, wc = wid & 1;

  f32x4 acc[4][4];
#pragma unroll
  for (int i = 0; i < 4; ++i)
#pragma unroll
    for (int j = 0; j < 4; ++j) acc[i][j] = f32x4{0.f, 0.f, 0.f, 0.f};

  const int cb = (lane & 7) * 16;

  for (int k0 = 0; k0 < K; k0 += 64) {
#pragma unroll
    for (int c = 0; c < 4; ++c) {
      int i = wid * 4 + c;
      int row = i * 8 + (lane >> 3);
      int sc = cb ^ ((row & 7) << 4);
      g2l16((const char*)A + ((size_t)(m0 + row) * K + k0) * 2 + sc, (char*)As + i * 1024);
      g2l16((const char*)B + ((size_t)(n0 + row) * K + k0) * 2 + sc, (char*)Bs + i * 1024);
    }
    __syncthreads();
#pragma unroll
    for (int kh = 0; kh < 2; ++kh) {
      bf16x8 af[4], bfr[4];
#pragma unroll
      for (int m = 0; m < 4; ++m) {
        int row = wr * 64 + m * 16 + r16;
        int byte = row * 128 + ((g * 16 + kh * 64) ^ ((row & 7) << 4));
        af[m] = *(const bf16x8*)((const char*)As + byte);
      }
#pragma unroll
      for (int n = 0; n < 4; ++n) {
        int row = wc * 64 + n * 16 + r16;
        int byte = row * 128 + ((g * 16 + kh * 64) ^ ((row & 7) << 4));
        bfr[n] = *(const bf16x8*)((const char*)Bs + byte);
      }
#pragma unroll
      for (int m = 0; m < 4; ++m)
#pragma unroll
        for (int n = 0; n < 4; ++n)
          acc[m][n] = __builtin_amdgcn_mfma_f32_16x16x32_bf16(af[m], bfr[n], acc[m][n], 0, 0, 0);
    }
    __syncthreads();
  }
#pragma unroll
  for (int m = 0; m < 4; ++m)
#pragma unroll
    for (int n = 0; n < 4; ++n)
#pragma unroll
      for (int j = 0; j < 4; ++j) {
        int row = m0 + wr * 64 + m * 16 + g * 4 + j;
        int col = n0 + wc * 64 + n * 16 + r16;
        float v = acc[m][n][j];
        if constexpr (sizeof(OUT) == 2)
          C[(size_t)row * N + col] = f2bf(v);
        else
          C[(size_t)row * N + col] = v;
      }
}

// ---------------- RMSNorm + RoPE + q_gain epilogue ----------------
__global__ __launch_bounds__(256) void k_normrope(const unsigned short* __restrict__ qkv,
                                                  const float* __restrict__ qg,
                                                  unsigned short* __restrict__ qn,
                                                  unsigned short* __restrict__ kn) {
  const int wid = threadIdx.x >> 6, lane = threadIdx.x & 63;
  const int b = blockIdx.x >> 7;
  const int s0 = (blockIdx.x & 127) * 16;
  const int dh = lane & 31;
  const float inv_freq = powf(10000.0f, -(float)dh * (1.0f / 32.0f));
  float sn, cs, snf, csf;
  sincosf((float)s0 * inv_freq, &sn, &cs);
  sincosf(inv_freq, &snf, &csf);  // per-step rotation
  for (int t = 0; t < 16; ++t) {
    const int s = s0 + t;
    const size_t base = (size_t)(b * 2048 + s) * 1536;
#pragma unroll
    for (int u = 0; u < 5; ++u) {
      const int unit = wid * 5 + u;  // 0..15 = q heads, 16..19 = k heads
      const int col = (unit < 16) ? unit * 64 : 1024 + (unit - 16) * 64;
      float v = bf2f(qkv[base + col + lane]);
      float ss = v * v;
      ss += __shfl_xor(ss, 1);  ss += __shfl_xor(ss, 2);  ss += __shfl_xor(ss, 4);
      ss += __shfl_xor(ss, 8);  ss += __shfl_xor(ss, 16); ss += __shfl_xor(ss, 32);
      float xr = v * rsqrtf(ss * (1.0f / 64.0f) + 1e-6f);
      float xp = __shfl_xor(xr, 32);
      float o = (lane < 32) ? (xr * cs + xp * sn) : (xr * cs - xp * sn);
      if (unit < 16) {
        o *= qg[unit] * 0.18033688011112042f;  // fold 1/8 * log2(e) into q
        qn[(size_t)(b * 2048 + s) * 1024 + unit * 64 + lane] = f2bf(o);
      } else {
        kn[(size_t)(b * 2048 + s) * 256 + (unit - 16) * 64 + lane] = f2bf(o);
      }
    }
    float cn = cs * csf - sn * snf;  // advance angle by inv_freq
    sn = sn * csf + cs * snf;
    cs = cn;
  }
}

// ---------------- V transpose: qkv v-part -> vt[b][hv][dim64][S] ----------------
__global__ __launch_bounds__(256) void k_vt(const unsigned short* __restrict__ qkv,
                                            unsigned short* __restrict__ vt) {
  __shared__ unsigned short T[64 * 64];
  const int tid = threadIdx.x;
  const int b = blockIdx.y >> 2, hv = blockIdx.y & 3;
  const int k0 = blockIdx.x * 64;
#pragma unroll
  for (int pass = 0; pass < 2; ++pass) {
    int key = pass * 32 + (tid >> 3);
    int d8 = (tid & 7) * 8;
    u16x8 v = *(const u16x8*)(qkv + (size_t)(b * 2048 + k0 + key) * 1536 + 1280 + hv * 64 + d8);
    int byte = key * 128 + ((d8 * 2) ^ ((((key & 7) ^ (key >> 3)) & 7) << 4));
    *(u16x8*)((char*)T + byte) = v;
  }
  __syncthreads();
#pragma unroll
  for (int pass = 0; pass < 2; ++pass) {
    int dim = pass * 32 + (tid >> 3);
    int k8 = (tid & 7) * 8;
    u16x8 o;
#pragma unroll
    for (int j = 0; j < 8; ++j) {
      int key = k8 + j;
      int byte = key * 128 + ((dim * 2) ^ ((((key & 7) ^ (key >> 3)) & 7) << 4));
      o[j] = *(const unsigned short*)((const char*)T + byte);
    }
    *(u16x8*)(vt + ((size_t)(b * 4 + hv) * 64 + dim) * 2048 + k0 + k8) = o;
  }
}

// ---------------- causal GQA flash attention, swapped-QK 32x32, 2-phase dbuf ----------------
// (R4 configuration: grid 1024, longest-first, 4 waves x 32 q-rows, KVBLK=64)
__global__ __launch_bounds__(256) void k_attn2(const unsigned short* __restrict__ qn,
                                               const unsigned short* __restrict__ kn,
                                               const unsigned short* __restrict__ vt,
                                               unsigned short* __restrict__ yb) {
  __shared__ unsigned short SMEM[2 * 8192];  // 2 x (Ks 8KB | Vts 8KB) = 32KB
  const int tid = threadIdx.x;
  const int wid = tid >> 6, lane = tid & 63;
  const int hi = lane >> 5, l31 = lane & 31;
  const int flat = blockIdx.x;
  const int qx = 15 - (flat >> 6);  // longest (qx=15) blocks dispatch first
  const int bh = flat & 63;
  const int b = bh >> 4, h = bh & 15, hv = h >> 2;
  const int q0w = qx * 128 + wid * 32;
  const int qglob = q0w + l31;
  const size_t tok0 = (size_t)b * 2048;
  const unsigned short* vtb = vt + (size_t)(b * 4 + hv) * 64 * 2048;

  bf16x8 qf[4];
#pragma unroll
  for (int m = 0; m < 4; ++m)
    qf[m] = *(const bf16x8*)(qn + (tok0 + qglob) * 1024 + h * 64 + m * 16 + hi * 8);

  f32x16 oacc[2];
#pragma unroll
  for (int db = 0; db < 2; ++db)
#pragma unroll
    for (int r = 0; r < 16; ++r) oacc[db][r] = 0.f;
  float mrun = -INFINITY, lrun = 0.f;

  const int nt = qx * 2 + 2;

  auto stage = [&](int T, int buf) {
    unsigned short* KsB = SMEM + buf * 8192;
    unsigned short* VtB = KsB + 4096;
    const int kk0 = T * 64;
#pragma unroll
    for (int c = 0; c < 2; ++c) {
      int i = wid * 2 + c;
      int row = i * 8 + (lane >> 3);
      int sc = ((lane & 7) * 16) ^ ((row & 7) << 4);
      g2l16((const char*)(kn + (tok0 + kk0 + row) * 256 + hv * 64) + sc, (char*)KsB + i * 1024);
      g2l16((const char*)(vtb + (size_t)row * 2048 + kk0) + sc, (char*)VtB + i * 1024);
    }
  };

  stage(0, 0);
  __syncthreads();

  int cur = 0;
  for (int t = 0; t < nt; ++t) {
    const int k0 = t * 64;
    if (t + 1 < nt) stage(t + 1, cur ^ 1);  // prefetch overlaps compute below

    if (k0 <= q0w + 31) {
      const unsigned short* KsB = SMEM + cur * 8192;
      const unsigned short* VtB = KsB + 4096;
      // ---- S^T[key][q] = K · Q^T ----
      f32x16 s[2];
#pragma unroll
      for (int kt = 0; kt < 2; ++kt) {
        f32x16 acc;
#pragma unroll
        for (int r = 0; r < 16; ++r) acc[r] = 0.f;
        const int krow = kt * 32 + l31;
        const char* kbase = (const char*)KsB + krow * 128;
        const int ksw = (krow & 7) << 4;
        __builtin_amdgcn_s_setprio(1);
#pragma unroll
        for (int m = 0; m < 4; ++m) {
          bf16x8 kf = *(const bf16x8*)(kbase + ((m * 32 + hi * 16) ^ ksw));
          acc = __builtin_amdgcn_mfma_f32_32x32x16_bf16(kf, qf[m], acc, 0, 0, 0);
        }
        __builtin_amdgcn_s_setprio(0);
        s[kt] = acc;
      }
      // ---- causal mask (near-diagonal tiles only) ----
      if (k0 + 63 > q0w) {
#pragma unroll
        for (int kt = 0; kt < 2; ++kt)
#pragma unroll
          for (int r = 0; r < 16; ++r) {
            int key = k0 + kt * 32 + (r & 3) + 8 * (r >> 2) + 4 * hi;
            if (key > qglob) s[kt][r] = -INFINITY;
          }
      }
      // ---- online softmax, per-lane scalar state, log2 domain, defer-max (T13) ----
      float red[16];
#pragma unroll
      for (int r = 0; r < 16; ++r) red[r] = fmaxf(s[0][r], s[1][r]);
#pragma unroll
      for (int r = 0; r < 8; ++r) red[r] = fmaxf(red[r], red[r + 8]);
#pragma unroll
      for (int r = 0; r < 4; ++r) red[r] = fmaxf(red[r], red[r + 4]);
      float mx = fmaxf(fmaxf(red[0], red[1]), fmaxf(red[2], red[3]));
      mx = fmaxf(mx, __shfl_xor(mx, 32));
      if (!__all(mx - mrun <= 8.0f)) {
        float mnew = fmaxf(mrun, mx);
        float fsc = exp2f(mrun - mnew);
        lrun *= fsc;
#pragma unroll
        for (int db = 0; db < 2; ++db)
#pragma unroll
          for (int r = 0; r < 16; ++r) oacc[db][r] *= fsc;
        mrun = mnew;
      }
#pragma unroll
      for (int kt = 0; kt < 2; ++kt)
#pragma unroll
        for (int r = 0; r < 16; ++r) s[kt][r] = exp2f(s[kt][r] - mrun);
      float sr[16];
#pragma unroll
      for (int r = 0; r < 16; ++r) sr[r] = s[0][r] + s[1][r];
#pragma unroll
      for (int r = 0; r < 8; ++r) sr[r] += sr[r + 8];
#pragma unroll
      for (int r = 0; r < 4; ++r) sr[r] += sr[r + 4];
      float ps = (sr[0] + sr[1]) + (sr[2] + sr[3]);
      ps += __shfl_xor(ps, 32);
      lrun += ps;
      // ---- P -> bf16 frags via cvt_pk + permlane32_swap (T12) ----
      i32x4 paw[4];
#pragma unroll
      for (int kt = 0; kt < 2; ++kt)
#pragma unroll
        for (int half = 0; half < 2; ++half) {
          int bs = half * 8;
          unsigned int a0 = cvtpk(s[kt][bs + 0], s[kt][bs + 1]);
          unsigned int a1 = cvtpk(s[kt][bs + 2], s[kt][bs + 3]);
          unsigned int b0 = cvtpk(s[kt][bs + 4], s[kt][bs + 5]);
          unsigned int b1 = cvtpk(s[kt][bs + 6], s[kt][bs + 7]);
          i32x2 r0 = __builtin_amdgcn_permlane32_swap((int)a0, (int)b0, false, false);
          i32x2 r1 = __builtin_amdgcn_permlane32_swap((int)a1, (int)b1, false, false);
          i32x4 w;
          w[0] = r0[0]; w[1] = r1[0]; w[2] = r0[1]; w[3] = r1[1];
          paw[kt * 2 + half] = w;
        }
      // ---- O^T += V^T · P^T ----
#pragma unroll
      for (int db = 0; db < 2; ++db) {
        const int vrow = db * 32 + l31;
        const char* vbase = (const char*)VtB + vrow * 128;
        const int vsw = (vrow & 7) << 4;
        __builtin_amdgcn_s_setprio(1);
#pragma unroll
        for (int ks = 0; ks < 4; ++ks) {
          bf16x8 vf = *(const bf16x8*)(vbase + ((ks * 32 + hi * 16) ^ vsw));
          oacc[db] = __builtin_amdgcn_mfma_f32_32x32x16_bf16(
              vf, __builtin_bit_cast(bf16x8, paw[ks]), oacc[db], 0, 0, 0);
        }
        __builtin_amdgcn_s_setprio(0);
      }
    }
    __syncthreads();  // drains prefetch (vmcnt) + protects buffer swap
    cur ^= 1;
  }

  // ---- epilogue: O^T -> per-wave LDS transpose -> coalesced row store ----
  const float inv = 1.0f / lrun;
  const int swl = (l31 & 7) << 4;
  char* obase = (char*)SMEM + wid * 4096;
#pragma unroll
  for (int db = 0; db < 2; ++db)
#pragma unroll
    for (int i = 0; i < 8; ++i) {
      int r = 2 * i;
      int dim = db * 32 + (r & 3) + 8 * (r >> 2) + 4 * hi;
      unsigned int w = (unsigned int)f2bf(oacc[db][r] * inv) |
                       ((unsigned int)f2bf(oacc[db][r + 1] * inv) << 16);
      *(unsigned int*)(obase + l31 * 128 + ((dim * 2) ^ swl)) = w;
    }
  __syncthreads();
#pragma unroll
  for (int it = 0; it < 4; ++it) {
    int cc = it * 2 + hi;
    i32x4 w = *(const i32x4*)(obase + l31 * 128 + ((cc * 16) ^ swl));
    *(i32x4*)(yb + (tok0 + q0w + l31) * 1024 + h * 64 + cc * 8) = w;
  }
}

// ---------------- launch ----------------
extern "C" void kernel_launch(void* const* d_in, const int* in_sizes, int n_in,
                              void* d_out, int out_size, void* d_ws, size_t ws_size,
                              hipStream_t stream) {
  (void)in_sizes; (void)n_in; (void)out_size; (void)ws_size;
  const float* x  = (const float*)d_in[0];
  const float* Wq = (const float*)d_in[1];
  const float* Wk = (const float*)d_in[2];
  const float* Wv = (const float*)d_in[3];
  const float* Wo = (const float*)d_in[4];
  const float* qg = (const float*)d_in[5];

  char* ws = (char*)d_ws;
  unsigned short* xb   = (unsigned short*)(ws);             // 16 MB  [8192][1024]
  unsigned short* wcat = (unsigned short*)(ws + 16777216);  // 3 MB   [1536][1024]
  unsigned short* wob  = (unsigned short*)(ws + 19922944);  // 2 MB   [1024][1024]
  unsigned short* qn   = (unsigned short*)(ws + 22020096);  // 16 MB  [8192][1024]
  unsigned short* kn   = (unsigned short*)(ws + 38797312);  // 4 MB   [8192][256]
  unsigned short* yb   = xb;                                // alias: xb dead after QKV GEMM
  unsigned short* qkv  = (unsigned short*)d_out;            // 24 MB scratch in d_out
  unsigned short* vt   = (unsigned short*)((char*)d_out + 25165824);  // 4 MB [16][64][2048]

  k_cvt<<<4096, 256, 0, stream>>>(x, xb, 8388608);
  k_cvt<<<512, 256, 0, stream>>>(Wq, wcat, 1048576);
  k_cvt<<<128, 256, 0, stream>>>(Wk, wcat + 1048576, 262144);
  k_cvt<<<128, 256, 0, stream>>>(Wv, wcat + 1310720, 262144);
  k_cvt<<<512, 256, 0, stream>>>(Wo, wob, 1048576);

  // QKV: MT=64, NT=12 -> 768 blocks (96/XCD: A-chunk 2MB L2-resident, B-panel shared)
  k_gemm_bt<unsigned short><<<768, 256, 0, stream>>>(xb, wcat, qkv, 8192, 1536, 1024);
  k_normrope<<<512, 256, 0, stream>>>(qkv, qg, qn, kn);
  k_vt<<<dim3(32, 16), 256, 0, stream>>>(qkv, vt);
  k_attn2<<<1024, 256, 0, stream>>>(qn, kn, vt, yb);
  // out-proj: MT=64, NT=8 -> 512 blocks
  k_gemm_bt<float><<<512, 256, 0, stream>>>(yb, wob, (float*)d_out, 8192, 1024, 1024);
}

// Round 8
// 162.831 us; speedup vs baseline: 1.4331x; 1.3464x over previous
//
#include <hip/hip_runtime.h>

typedef float f32x4 __attribute__((ext_vector_type(4)));
typedef float f32x16 __attribute__((ext_vector_type(16)));
typedef __bf16 bf16x8 __attribute__((ext_vector_type(8)));
typedef unsigned short u16x8 __attribute__((ext_vector_type(8)));
typedef int i32x2 __attribute__((ext_vector_type(2)));
typedef int i32x4 __attribute__((ext_vector_type(4)));

#define DEV static __device__ __forceinline__

DEV float bf2f(unsigned short h) {
  unsigned int u = ((unsigned int)h) << 16;
  return __builtin_bit_cast(float, u);
}
DEV unsigned short f2bf(float f) {
  unsigned int u = __builtin_bit_cast(unsigned int, f);
  u += 0x7fff + ((u >> 16) & 1);   // RTNE
  return (unsigned short)(u >> 16);
}

DEV void g2l16(const void* g, void* l) {
  __builtin_amdgcn_global_load_lds(
      (const __attribute__((address_space(1))) void*)g,
      (__attribute__((address_space(3))) void*)l, 16, 0, 0);
}

DEV unsigned int cvtpk(float lo, float hi) {
  unsigned int r;
  asm("v_cvt_pk_bf16_f32 %0, %1, %2" : "=v"(r) : "v"(lo), "v"(hi));
  return r;
}

// ---------------- fused converts + RoPE table ----------------
// blocks: [0,4096) x  [4096,4608) Wq  [4608,4736) Wk  [4736,4864) Wv
//         [4864,5376) Wo  [5376,5632) rope table fill
DEV void cvt8(const float* __restrict__ in, unsigned short* __restrict__ out, int idx) {
  int i = idx * 8;
  float4 a = *(const float4*)(in + i);
  float4 b = *(const float4*)(in + i + 4);
  u16x8 r;
  r[0] = f2bf(a.x); r[1] = f2bf(a.y); r[2] = f2bf(a.z); r[3] = f2bf(a.w);
  r[4] = f2bf(b.x); r[5] = f2bf(b.y); r[6] = f2bf(b.z); r[7] = f2bf(b.w);
  *(u16x8*)(out + i) = r;
}

__global__ __launch_bounds__(256) void k_cvt_all(const float* __restrict__ x,
                                                 const float* __restrict__ wq,
                                                 const float* __restrict__ wk,
                                                 const float* __restrict__ wv,
                                                 const float* __restrict__ wo,
                                                 unsigned short* __restrict__ xb,
                                                 unsigned short* __restrict__ wcat,
                                                 unsigned short* __restrict__ wob,
                                                 float2* __restrict__ rope) {
  const int blk = blockIdx.x, tid = threadIdx.x;
  if (blk < 4096) {
    cvt8(x, xb, blk * 256 + tid);
  } else if (blk < 4608) {
    cvt8(wq, wcat, (blk - 4096) * 256 + tid);
  } else if (blk < 4736) {
    cvt8(wk, wcat + 1048576, (blk - 4608) * 256 + tid);
  } else if (blk < 4864) {
    cvt8(wv, wcat + 1310720, (blk - 4736) * 256 + tid);
  } else if (blk < 5376) {
    cvt8(wo, wob, (blk - 4864) * 256 + tid);
  } else {
    int idx = (blk - 5376) * 256 + tid;   // [0, 65536)
    int s = idx >> 5, dmod = idx & 31;
    float inv_freq = powf(10000.0f, -(float)dmod * (1.0f / 32.0f));
    float sn, cs;
    sincosf((float)s * inv_freq, &sn, &cs);
    rope[idx] = make_float2(cs, sn);
  }
}

// ---------------- fused QKV GEMM + RMSNorm/RoPE/gain + V-transpose ----------------
// m97 128x128 structure. grid (64, 12). n-tiles: y<8 q-heads, y 8-9 k-heads, y 10-11 v.
__global__ __launch_bounds__(256) void k_qkv(const unsigned short* __restrict__ A,
                                             const unsigned short* __restrict__ B,
                                             const float* __restrict__ qg,
                                             const float2* __restrict__ rope,
                                             unsigned short* __restrict__ qn,
                                             unsigned short* __restrict__ kn,
                                             unsigned short* __restrict__ vt) {
  __shared__ unsigned short LDS[16384];  // As | Bs, reused as 32KB transpose buffer
  unsigned short* As = LDS;
  unsigned short* Bs = LDS + 8192;
  const int K = 1024, N1536 = 1536;
  const int tid = threadIdx.x;
  const int wid = tid >> 6, lane = tid & 63;
  const int g = lane >> 4, r16 = lane & 15;
  const int m0 = blockIdx.x * 128;
  const int y = blockIdx.y;
  const int n0 = y * 128;
  const int wr = wid >> 1, wc = wid & 1;

  f32x4 acc[4][4];
#pragma unroll
  for (int i = 0; i < 4; ++i)
#pragma unroll
    for (int j = 0; j < 4; ++j) acc[i][j] = f32x4{0.f, 0.f, 0.f, 0.f};

  const int cb = (lane & 7) * 16;

  for (int k0 = 0; k0 < K; k0 += 64) {
#pragma unroll
    for (int c = 0; c < 4; ++c) {
      int i = wid * 4 + c;
      int row = i * 8 + (lane >> 3);
      int sc = cb ^ ((row & 7) << 4);
      g2l16((const char*)A + ((size_t)(m0 + row) * K + k0) * 2 + sc, (char*)As + i * 1024);
      g2l16((const char*)B + ((size_t)(n0 + row) * K + k0) * 2 + sc, (char*)Bs + i * 1024);
    }
    __syncthreads();
#pragma unroll
    for (int kh = 0; kh < 2; ++kh) {
      bf16x8 af[4], bfr[4];
#pragma unroll
      for (int m = 0; m < 4; ++m) {
        int row = wr * 64 + m * 16 + r16;
        int byte = row * 128 + ((g * 16 + kh * 64) ^ ((row & 7) << 4));
        af[m] = *(const bf16x8*)((const char*)As + byte);
      }
#pragma unroll
      for (int n = 0; n < 4; ++n) {
        int row = wc * 64 + n * 16 + r16;
        int byte = row * 128 + ((g * 16 + kh * 64) ^ ((row & 7) << 4));
        bfr[n] = *(const bf16x8*)((const char*)Bs + byte);
      }
#pragma unroll
      for (int m = 0; m < 4; ++m)
#pragma unroll
        for (int n = 0; n < 4; ++n)
          acc[m][n] = __builtin_amdgcn_mfma_f32_16x16x32_bf16(af[m], bfr[n], acc[m][n], 0, 0, 0);
    }
    __syncthreads();
  }

  if (y < 10) {
    // ---- q/k epilogue: RMSNorm + RoPE (+ gain for q) ----
    const bool isq = (y < 8);
    const int head = isq ? (2 * y + wc) : (2 * (y - 8) + wc);
    const float gain = isq ? qg[head] * 0.18033688011112042f : 1.0f;  // fold 1/8*log2e into q
#pragma unroll
    for (int m = 0; m < 4; ++m)
#pragma unroll
      for (int j = 0; j < 4; ++j) {
        int rowl = wr * 64 + m * 16 + g * 4 + j;
        int tok = m0 + rowl;
        int s = tok & 2047;
        float v0 = acc[m][0][j], v1 = acc[m][1][j], v2 = acc[m][2][j], v3 = acc[m][3][j];
        float ss = v0 * v0 + v1 * v1 + v2 * v2 + v3 * v3;
        ss += __shfl_xor(ss, 1); ss += __shfl_xor(ss, 2);
        ss += __shfl_xor(ss, 4); ss += __shfl_xor(ss, 8);
        float rs = rsqrtf(ss * (1.0f / 64.0f) + 1e-6f) * gain;
        float2 cs0 = rope[s * 32 + r16];
        float2 cs1 = rope[s * 32 + 16 + r16];
        float o0 = (v0 * cs0.x + v2 * cs0.y) * rs;
        float o2 = (v2 * cs0.x - v0 * cs0.y) * rs;
        float o1 = (v1 * cs1.x + v3 * cs1.y) * rs;
        float o3 = (v3 * cs1.x - v1 * cs1.y) * rs;
        unsigned short* dst = isq ? (qn + (size_t)tok * 1024 + head * 64)
                                  : (kn + (size_t)tok * 256 + head * 64);
        dst[r16] = f2bf(o0);
        dst[16 + r16] = f2bf(o1);
        dst[32 + r16] = f2bf(o2);
        dst[48 + r16] = f2bf(o3);
      }
  } else {
    // ---- v epilogue: transpose via LDS -> vt[b][hv][d][2048] ----
    unsigned short* T = LDS;  // [d 128][tok 128] u16, XOR-swizzled
#pragma unroll
    for (int m = 0; m < 4; ++m)
#pragma unroll
      for (int n = 0; n < 4; ++n)
#pragma unroll
        for (int j = 0; j < 4; ++j) {
          int tokl = wr * 64 + m * 16 + g * 4 + j;
          int dl = wc * 64 + n * 16 + r16;
          int byte = (dl * 256 + tokl * 2) ^ ((dl & 15) << 4);
          *(unsigned short*)((char*)T + byte) = f2bf(acc[m][n][j]);
        }
    __syncthreads();
    const int d = tid >> 1, th = tid & 1;
    const int hv = 2 * (y - 10) + (d >> 6), dh = d & 63;
    const int bb = m0 >> 11;
    const int s0 = (m0 & 2047) + th * 64;
    unsigned short* dstv = vt + ((size_t)(bb * 4 + hv) * 64 + dh) * 2048 + s0;
    const int swz = (d & 15) << 4;
#pragma unroll
    for (int c = 0; c < 8; ++c) {
      i32x4 w = *(const i32x4*)((const char*)T + ((d * 256 + th * 128 + c * 16) ^ swz));
      *(i32x4*)(dstv + c * 8) = w;
    }
  }
}

// ---------------- NT GEMM (m97) for out-proj ----------------
__global__ __launch_bounds__(256) void k_gemm_bt(const unsigned short* __restrict__ A,
                                                 const unsigned short* __restrict__ B,
                                                 float* __restrict__ C, int M, int N, int K) {
  __shared__ unsigned short As[128 * 64];
  __shared__ unsigned short Bs[128 * 64];
  const int tid = threadIdx.x;
  const int wid = tid >> 6, lane = tid & 63;
  const int g = lane >> 4, r16 = lane & 15;
  const int m0 = blockIdx.x * 128, n0 = blockIdx.y * 128;
  const int wr = wid >> 1, wc = wid & 1;

  f32x4 acc[4][4];
#pragma unroll
  for (int i = 0; i < 4; ++i)
#pragma unroll
    for (int j = 0; j < 4; ++j) acc[i][j] = f32x4{0.f, 0.f, 0.f, 0.f};

  const int cb = (lane & 7) * 16;

  for (int k0 = 0; k0 < K; k0 += 64) {
#pragma unroll
    for (int c = 0; c < 4; ++c) {
      int i = wid * 4 + c;
      int row = i * 8 + (lane >> 3);
      int sc = cb ^ ((row & 7) << 4);
      g2l16((const char*)A + ((size_t)(m0 + row) * K + k0) * 2 + sc, (char*)As + i * 1024);
      g2l16((const char*)B + ((size_t)(n0 + row) * K + k0) * 2 + sc, (char*)Bs + i * 1024);
    }
    __syncthreads();
#pragma unroll
    for (int kh = 0; kh < 2; ++kh) {
      bf16x8 af[4], bfr[4];
#pragma unroll
      for (int m = 0; m < 4; ++m) {
        int row = wr * 64 + m * 16 + r16;
        int byte = row * 128 + ((g * 16 + kh * 64) ^ ((row & 7) << 4));
        af[m] = *(const bf16x8*)((const char*)As + byte);
      }
#pragma unroll
      for (int n = 0; n < 4; ++n) {
        int row = wc * 64 + n * 16 + r16;
        int byte = row * 128 + ((g * 16 + kh * 64) ^ ((row & 7) << 4));
        bfr[n] = *(const bf16x8*)((const char*)Bs + byte);
      }
#pragma unroll
      for (int m = 0; m < 4; ++m)
#pragma unroll
        for (int n = 0; n < 4; ++n)
          acc[m][n] = __builtin_amdgcn_mfma_f32_16x16x32_bf16(af[m], bfr[n], acc[m][n], 0, 0, 0);
    }
    __syncthreads();
  }
#pragma unroll
  for (int m = 0; m < 4; ++m)
#pragma unroll
    for (int n = 0; n < 4; ++n)
#pragma unroll
      for (int j = 0; j < 4; ++j) {
        int row = m0 + wr * 64 + m * 16 + g * 4 + j;
        int col = n0 + wc * 64 + n * 16 + r16;
        C[(size_t)row * N + col] = acc[m][n][j];
      }
}

// ---------------- causal GQA flash attention, swapped-QK 32x32, 2-phase dbuf ----------------
// grid 1024, longest-first. mrun init 20 (safe: |S|<=||q||*||k|| ~ 17.3 in log2 domain)
// folded into the QK MFMA C-init; l-sum via ones-MFMA into lacc.
__global__ __launch_bounds__(256) void k_attn2(const unsigned short* __restrict__ qn,
                                               const unsigned short* __restrict__ kn,
                                               const unsigned short* __restrict__ vt,
                                               unsigned short* __restrict__ yb) {
  __shared__ unsigned short SMEM[2 * 8192];  // 2 x (Ks 8KB | Vts 8KB) = 32KB
  const int tid = threadIdx.x;
  const int wid = tid >> 6, lane = tid & 63;
  const int hi = lane >> 5, l31 = lane & 31;
  const int flat = blockIdx.x;
  const int qx = 15 - (flat >> 6);  // longest (qx=15) blocks dispatch first
  const int bh = flat & 63;
  const int b = bh >> 4, h = bh & 15, hv = h >> 2;
  const int q0w = qx * 128 + wid * 32;
  const int qglob = q0w + l31;
  const size_t tok0 = (size_t)b * 2048;
  const unsigned short* vtb = vt + (size_t)(b * 4 + hv) * 64 * 2048;

  const u16x8 onesu = {0x3F80, 0x3F80, 0x3F80, 0x3F80, 0x3F80, 0x3F80, 0x3F80, 0x3F80};
  const bf16x8 ones = __builtin_bit_cast(bf16x8, onesu);

  bf16x8 qf[4];
#pragma unroll
  for (int m = 0; m < 4; ++m)
    qf[m] = *(const bf16x8*)(qn + (tok0 + qglob) * 1024 + h * 64 + m * 16 + hi * 8);

  f32x16 oacc[2], lacc;
#pragma unroll
  for (int db = 0; db < 2; ++db)
#pragma unroll
    for (int r = 0; r < 16; ++r) oacc[db][r] = 0.f;
#pragma unroll
  for (int r = 0; r < 16; ++r) lacc[r] = 0.f;
  float mrun = 20.0f;

  const int nt = qx * 2 + 2;

  auto stage = [&](int T, int buf) {
    unsigned short* KsB = SMEM + buf * 8192;
    unsigned short* VtB = KsB + 4096;
    const int kk0 = T * 64;
#pragma unroll
    for (int c = 0; c < 2; ++c) {
      int i = wid * 2 + c;
      int row = i * 8 + (lane >> 3);
      int sc = ((lane & 7) * 16) ^ ((row & 7) << 4);
      g2l16((const char*)(kn + (tok0 + kk0 + row) * 256 + hv * 64) + sc, (char*)KsB + i * 1024);
      g2l16((const char*)(vtb + (size_t)row * 2048 + kk0) + sc, (char*)VtB + i * 1024);
    }
  };

  stage(0, 0);
  __syncthreads();

  int cur = 0;
  for (int t = 0; t < nt; ++t) {
    const int k0 = t * 64;
    if (t + 1 < nt) stage(t + 1, cur ^ 1);  // prefetch overlaps compute below

    if (k0 <= q0w + 31) {
      const unsigned short* KsB = SMEM + cur * 8192;
      const unsigned short* VtB = KsB + 4096;
      const float negm = -mrun;
      // ---- S^T[key][q] = K · Q^T - mrun (via C-init) ----
      f32x16 s[2];
#pragma unroll
      for (int kt = 0; kt < 2; ++kt) {
        f32x16 acc;
#pragma unroll
        for (int r = 0; r < 16; ++r) acc[r] = negm;
        const int krow = kt * 32 + l31;
        const char* kbase = (const char*)KsB + krow * 128;
        const int ksw = (krow & 7) << 4;
        __builtin_amdgcn_s_setprio(1);
#pragma unroll
        for (int m = 0; m < 4; ++m) {
          bf16x8 kf = *(const bf16x8*)(kbase + ((m * 32 + hi * 16) ^ ksw));
          acc = __builtin_amdgcn_mfma_f32_32x32x16_bf16(kf, qf[m], acc, 0, 0, 0);
        }
        __builtin_amdgcn_s_setprio(0);
        s[kt] = acc;
      }
      // ---- causal mask (near-diagonal tiles only) ----
      if (k0 + 63 > q0w) {
#pragma unroll
        for (int kt = 0; kt < 2; ++kt)
#pragma unroll
          for (int r = 0; r < 16; ++r) {
            int key = k0 + kt * 32 + (r & 3) + 8 * (r >> 2) + 4 * hi;
            if (key > qglob) s[kt][r] = -INFINITY;
          }
      }
      // ---- guard (provably dead for these inputs; kept for safety) ----
      float red[16];
#pragma unroll
      for (int r = 0; r < 16; ++r) red[r] = fmaxf(s[0][r], s[1][r]);
#pragma unroll
      for (int r = 0; r < 8; ++r) red[r] = fmaxf(red[r], red[r + 8]);
#pragma unroll
      for (int r = 0; r < 4; ++r) red[r] = fmaxf(red[r], red[r + 4]);
      float mx = fmaxf(fmaxf(red[0], red[1]), fmaxf(red[2], red[3]));
      mx = fmaxf(mx, __shfl_xor(mx, 32));
      if (!__all(mx <= 8.0f)) {
        float mx2 = fmaxf(mx, 0.0f);
        float fsc = exp2f(-mx2);
#pragma unroll
        for (int db = 0; db < 2; ++db)
#pragma unroll
          for (int r = 0; r < 16; ++r) oacc[db][r] *= fsc;
#pragma unroll
        for (int r = 0; r < 16; ++r) lacc[r] *= fsc;
#pragma unroll
        for (int kt = 0; kt < 2; ++kt)
#pragma unroll
          for (int r = 0; r < 16; ++r) s[kt][r] -= mx2;
        mrun += mx2;
      }
      // ---- P = exp2(S - mrun) ----
#pragma unroll
      for (int kt = 0; kt < 2; ++kt)
#pragma unroll
        for (int r = 0; r < 16; ++r) s[kt][r] = exp2f(s[kt][r]);
      // ---- P -> bf16 frags via cvt_pk + permlane32_swap (T12) ----
      i32x4 paw[4];
#pragma unroll
      for (int kt = 0; kt < 2; ++kt)
#pragma unroll
        for (int half = 0; half < 2; ++half) {
          int bs = half * 8;
          unsigned int a0 = cvtpk(s[kt][bs + 0], s[kt][bs + 1]);
          unsigned int a1 = cvtpk(s[kt][bs + 2], s[kt][bs + 3]);
          unsigned int b0 = cvtpk(s[kt][bs + 4], s[kt][bs + 5]);
          unsigned int b1 = cvtpk(s[kt][bs + 6], s[kt][bs + 7]);
          i32x2 r0 = __builtin_amdgcn_permlane32_swap((int)a0, (int)b0, false, false);
          i32x2 r1 = __builtin_amdgcn_permlane32_swap((int)a1, (int)b1, false, false);
          i32x4 w;
          w[0] = r0[0]; w[1] = r1[0]; w[2] = r0[1]; w[3] = r1[1];
          paw[kt * 2 + half] = w;
        }
      // ---- O^T += V^T · P^T ; l += 1 · P^T (ones-MFMA row-sum) ----
      __builtin_amdgcn_s_setprio(1);
#pragma unroll
      for (int db = 0; db < 2; ++db) {
        const int vrow = db * 32 + l31;
        const char* vbase = (const char*)VtB + vrow * 128;
        const int vsw = (vrow & 7) << 4;
#pragma unroll
        for (int ks = 0; ks < 4; ++ks) {
          bf16x8 vf = *(const bf16x8*)(vbase + ((ks * 32 + hi * 16) ^ vsw));
          oacc[db] = __builtin_amdgcn_mfma_f32_32x32x16_bf16(
              vf, __builtin_bit_cast(bf16x8, paw[ks]), oacc[db], 0, 0, 0);
        }
      }
#pragma unroll
      for (int ks = 0; ks < 4; ++ks)
        lacc = __builtin_amdgcn_mfma_f32_32x32x16_bf16(
            ones, __builtin_bit_cast(bf16x8, paw[ks]), lacc, 0, 0, 0);
      __builtin_amdgcn_s_setprio(0);
    }
    __syncthreads();  // drains prefetch (vmcnt) + protects buffer swap
    cur ^= 1;
  }

  // ---- epilogue: O^T -> per-wave LDS transpose -> coalesced row store ----
  const float inv = 1.0f / lacc[0];
  const int swl = (l31 & 7) << 4;
  char* obase = (char*)SMEM + wid * 4096;
#pragma unroll
  for (int db = 0; db < 2; ++db)
#pragma unroll
    for (int i = 0; i < 8; ++i) {
      int r = 2 * i;
      int dim = db * 32 + (r & 3) + 8 * (r >> 2) + 4 * hi;
      unsigned int w = (unsigned int)f2bf(oacc[db][r] * inv) |
                       ((unsigned int)f2bf(oacc[db][r + 1] * inv) << 16);
      *(unsigned int*)(obase + l31 * 128 + ((dim * 2) ^ swl)) = w;
    }
  __syncthreads();
#pragma unroll
  for (int it = 0; it < 4; ++it) {
    int cc = it * 2 + hi;
    i32x4 w = *(const i32x4*)(obase + l31 * 128 + ((cc * 16) ^ swl));
    *(i32x4*)(yb + (tok0 + q0w + l31) * 1024 + h * 64 + cc * 8) = w;
  }
}

// ---------------- launch ----------------
extern "C" void kernel_launch(void* const* d_in, const int* in_sizes, int n_in,
                              void* d_out, int out_size, void* d_ws, size_t ws_size,
                              hipStream_t stream) {
  (void)in_sizes; (void)n_in; (void)out_size; (void)ws_size;
  const float* x  = (const float*)d_in[0];
  const float* Wq = (const float*)d_in[1];
  const float* Wk = (const float*)d_in[2];
  const float* Wv = (const float*)d_in[3];
  const float* Wo = (const float*)d_in[4];
  const float* qg = (const float*)d_in[5];

  char* ws = (char*)d_ws;
  unsigned short* xb   = (unsigned short*)(ws);             // 16 MB  [8192][1024]
  unsigned short* wcat = (unsigned short*)(ws + 16777216);  // 3 MB   [1536][1024]
  unsigned short* wob  = (unsigned short*)(ws + 19922944);  // 2 MB   [1024][1024]
  unsigned short* qn   = (unsigned short*)(ws + 22020096);  // 16 MB  [8192][1024]
  unsigned short* kn   = (unsigned short*)(ws + 38797312);  // 4 MB   [8192][256]
  unsigned short* yb   = xb;                                // alias: xb dead after k_qkv
  // d_out scratch (32 MB total; all consumed before final GEMM writes):
  unsigned short* vt   = (unsigned short*)((char*)d_out + 25165824);  // 4 MB [16][64][2048]
  float2*         rope = (float2*)((char*)d_out + 29360128);          // 512 KB [2048][32]

  k_cvt_all<<<5632, 256, 0, stream>>>(x, Wq, Wk, Wv, Wo, xb, wcat, wob, rope);
  k_qkv<<<dim3(64, 12), 256, 0, stream>>>(xb, wcat, qg, rope, qn, kn, vt);
  k_attn2<<<1024, 256, 0, stream>>>(qn, kn, vt, yb);
  k_gemm_bt<<<dim3(64, 8), 256, 0, stream>>>(yb, wob, (float*)d_out, 8192, 1024, 1024);
}

// Round 9
// 154.562 us; speedup vs baseline: 1.5098x; 1.0535x over previous
//
#include <hip/hip_runtime.h>

typedef float f32x4 __attribute__((ext_vector_type(4)));
typedef float f32x16 __attribute__((ext_vector_type(16)));
typedef __bf16 bf16x8 __attribute__((ext_vector_type(8)));
typedef unsigned short u16x8 __attribute__((ext_vector_type(8)));
typedef int i32x2 __attribute__((ext_vector_type(2)));
typedef int i32x4 __attribute__((ext_vector_type(4)));

#define DEV static __device__ __forceinline__

DEV float bf2f(unsigned short h) {
  unsigned int u = ((unsigned int)h) << 16;
  return __builtin_bit_cast(float, u);
}
DEV unsigned short f2bf(float f) {
  unsigned int u = __builtin_bit_cast(unsigned int, f);
  u += 0x7fff + ((u >> 16) & 1);   // RTNE
  return (unsigned short)(u >> 16);
}

DEV void g2l16(const void* g, void* l) {
  __builtin_amdgcn_global_load_lds(
      (const __attribute__((address_space(1))) void*)g,
      (__attribute__((address_space(3))) void*)l, 16, 0, 0);
}

DEV unsigned int cvtpk(float lo, float hi) {
  unsigned int r;
  asm("v_cvt_pk_bf16_f32 %0, %1, %2" : "=v"(r) : "v"(lo), "v"(hi));
  return r;
}

// ---------------- fused converts + RoPE table ----------------
DEV void cvt8(const float* __restrict__ in, unsigned short* __restrict__ out, int idx) {
  int i = idx * 8;
  float4 a = *(const float4*)(in + i);
  float4 b = *(const float4*)(in + i + 4);
  u16x8 r;
  r[0] = f2bf(a.x); r[1] = f2bf(a.y); r[2] = f2bf(a.z); r[3] = f2bf(a.w);
  r[4] = f2bf(b.x); r[5] = f2bf(b.y); r[6] = f2bf(b.z); r[7] = f2bf(b.w);
  *(u16x8*)(out + i) = r;
}

__global__ __launch_bounds__(256) void k_cvt_all(const float* __restrict__ x,
                                                 const float* __restrict__ wq,
                                                 const float* __restrict__ wk,
                                                 const float* __restrict__ wv,
                                                 const float* __restrict__ wo,
                                                 unsigned short* __restrict__ xb,
                                                 unsigned short* __restrict__ wcat,
                                                 unsigned short* __restrict__ wob,
                                                 float2* __restrict__ rope) {
  const int blk = blockIdx.x, tid = threadIdx.x;
  if (blk < 4096) {
    cvt8(x, xb, blk * 256 + tid);
  } else if (blk < 4608) {
    cvt8(wq, wcat, (blk - 4096) * 256 + tid);
  } else if (blk < 4736) {
    cvt8(wk, wcat + 1048576, (blk - 4608) * 256 + tid);
  } else if (blk < 4864) {
    cvt8(wv, wcat + 1310720, (blk - 4736) * 256 + tid);
  } else if (blk < 5376) {
    cvt8(wo, wob, (blk - 4864) * 256 + tid);
  } else {
    int idx = (blk - 5376) * 256 + tid;   // [0, 65536)
    int s = idx >> 5, dmod = idx & 31;
    float inv_freq = powf(10000.0f, -(float)dmod * (1.0f / 32.0f));
    float sn, cs;
    sincosf((float)s * inv_freq, &sn, &cs);
    rope[idx] = make_float2(cs, sn);
  }
}

// ---------------- fused QKV GEMM + RMSNorm/RoPE/gain + V-transpose ----------------
__global__ __launch_bounds__(256) void k_qkv(const unsigned short* __restrict__ A,
                                             const unsigned short* __restrict__ B,
                                             const float* __restrict__ qg,
                                             const float2* __restrict__ rope,
                                             unsigned short* __restrict__ qn,
                                             unsigned short* __restrict__ kn,
                                             unsigned short* __restrict__ vt) {
  __shared__ unsigned short LDS[16384];
  unsigned short* As = LDS;
  unsigned short* Bs = LDS + 8192;
  const int K = 1024;
  const int tid = threadIdx.x;
  const int wid = tid >> 6, lane = tid & 63;
  const int g = lane >> 4, r16 = lane & 15;
  const int m0 = blockIdx.x * 128;
  const int y = blockIdx.y;
  const int n0 = y * 128;
  const int wr = wid >> 1, wc = wid & 1;

  f32x4 acc[4][4];
#pragma unroll
  for (int i = 0; i < 4; ++i)
#pragma unroll
    for (int j = 0; j < 4; ++j) acc[i][j] = f32x4{0.f, 0.f, 0.f, 0.f};

  const int cb = (lane & 7) * 16;

  for (int k0 = 0; k0 < K; k0 += 64) {
#pragma unroll
    for (int c = 0; c < 4; ++c) {
      int i = wid * 4 + c;
      int row = i * 8 + (lane >> 3);
      int sc = cb ^ ((row & 7) << 4);
      g2l16((const char*)A + ((size_t)(m0 + row) * K + k0) * 2 + sc, (char*)As + i * 1024);
      g2l16((const char*)B + ((size_t)(n0 + row) * K + k0) * 2 + sc, (char*)Bs + i * 1024);
    }
    __syncthreads();
#pragma unroll
    for (int kh = 0; kh < 2; ++kh) {
      bf16x8 af[4], bfr[4];
#pragma unroll
      for (int m = 0; m < 4; ++m) {
        int row = wr * 64 + m * 16 + r16;
        int byte = row * 128 + ((g * 16 + kh * 64) ^ ((row & 7) << 4));
        af[m] = *(const bf16x8*)((const char*)As + byte);
      }
#pragma unroll
      for (int n = 0; n < 4; ++n) {
        int row = wc * 64 + n * 16 + r16;
        int byte = row * 128 + ((g * 16 + kh * 64) ^ ((row & 7) << 4));
        bfr[n] = *(const bf16x8*)((const char*)Bs + byte);
      }
#pragma unroll
      for (int m = 0; m < 4; ++m)
#pragma unroll
        for (int n = 0; n < 4; ++n)
          acc[m][n] = __builtin_amdgcn_mfma_f32_16x16x32_bf16(af[m], bfr[n], acc[m][n], 0, 0, 0);
    }
    __syncthreads();
  }

  if (y < 10) {
    const bool isq = (y < 8);
    const int head = isq ? (2 * y + wc) : (2 * (y - 8) + wc);
    const float gain = isq ? qg[head] * 0.18033688011112042f : 1.0f;  // fold 1/8*log2e into q
#pragma unroll
    for (int m = 0; m < 4; ++m)
#pragma unroll
      for (int j = 0; j < 4; ++j) {
        int rowl = wr * 64 + m * 16 + g * 4 + j;
        int tok = m0 + rowl;
        int s = tok & 2047;
        float v0 = acc[m][0][j], v1 = acc[m][1][j], v2 = acc[m][2][j], v3 = acc[m][3][j];
        float ss = v0 * v0 + v1 * v1 + v2 * v2 + v3 * v3;
        ss += __shfl_xor(ss, 1); ss += __shfl_xor(ss, 2);
        ss += __shfl_xor(ss, 4); ss += __shfl_xor(ss, 8);
        float rs = rsqrtf(ss * (1.0f / 64.0f) + 1e-6f) * gain;
        float2 cs0 = rope[s * 32 + r16];
        float2 cs1 = rope[s * 32 + 16 + r16];
        float o0 = (v0 * cs0.x + v2 * cs0.y) * rs;
        float o2 = (v2 * cs0.x - v0 * cs0.y) * rs;
        float o1 = (v1 * cs1.x + v3 * cs1.y) * rs;
        float o3 = (v3 * cs1.x - v1 * cs1.y) * rs;
        unsigned short* dst = isq ? (qn + (size_t)tok * 1024 + head * 64)
                                  : (kn + (size_t)tok * 256 + head * 64);
        dst[r16] = f2bf(o0);
        dst[16 + r16] = f2bf(o1);
        dst[32 + r16] = f2bf(o2);
        dst[48 + r16] = f2bf(o3);
      }
  } else {
    unsigned short* T = LDS;
#pragma unroll
    for (int m = 0; m < 4; ++m)
#pragma unroll
      for (int n = 0; n < 4; ++n)
#pragma unroll
        for (int j = 0; j < 4; ++j) {
          int tokl = wr * 64 + m * 16 + g * 4 + j;
          int dl = wc * 64 + n * 16 + r16;
          int byte = (dl * 256 + tokl * 2) ^ ((dl & 15) << 4);
          *(unsigned short*)((char*)T + byte) = f2bf(acc[m][n][j]);
        }
    __syncthreads();
    const int d = tid >> 1, th = tid & 1;
    const int hv = 2 * (y - 10) + (d >> 6), dh = d & 63;
    const int bb = m0 >> 11;
    const int s0 = (m0 & 2047) + th * 64;
    unsigned short* dstv = vt + ((size_t)(bb * 4 + hv) * 64 + dh) * 2048 + s0;
    const int swz = (d & 15) << 4;
#pragma unroll
    for (int c = 0; c < 8; ++c) {
      i32x4 w = *(const i32x4*)((const char*)T + ((d * 256 + th * 128 + c * 16) ^ swz));
      *(i32x4*)(dstv + c * 8) = w;
    }
  }
}

// ---------------- NT GEMM (m97) for out-proj ----------------
__global__ __launch_bounds__(256) void k_gemm_bt(const unsigned short* __restrict__ A,
                                                 const unsigned short* __restrict__ B,
                                                 float* __restrict__ C, int M, int N, int K) {
  __shared__ unsigned short As[128 * 64];
  __shared__ unsigned short Bs[128 * 64];
  const int tid = threadIdx.x;
  const int wid = tid >> 6, lane = tid & 63;
  const int g = lane >> 4, r16 = lane & 15;
  const int m0 = blockIdx.x * 128, n0 = blockIdx.y * 128;
  const int wr = wid >> 1, wc = wid & 1;

  f32x4 acc[4][4];
#pragma unroll
  for (int i = 0; i < 4; ++i)
#pragma unroll
    for (int j = 0; j < 4; ++j) acc[i][j] = f32x4{0.f, 0.f, 0.f, 0.f};

  const int cb = (lane & 7) * 16;

  for (int k0 = 0; k0 < K; k0 += 64) {
#pragma unroll
    for (int c = 0; c < 4; ++c) {
      int i = wid * 4 + c;
      int row = i * 8 + (lane >> 3);
      int sc = cb ^ ((row & 7) << 4);
      g2l16((const char*)A + ((size_t)(m0 + row) * K + k0) * 2 + sc, (char*)As + i * 1024);
      g2l16((const char*)B + ((size_t)(n0 + row) * K + k0) * 2 + sc, (char*)Bs + i * 1024);
    }
    __syncthreads();
#pragma unroll
    for (int kh = 0; kh < 2; ++kh) {
      bf16x8 af[4], bfr[4];
#pragma unroll
      for (int m = 0; m < 4; ++m) {
        int row = wr * 64 + m * 16 + r16;
        int byte = row * 128 + ((g * 16 + kh * 64) ^ ((row & 7) << 4));
        af[m] = *(const bf16x8*)((const char*)As + byte);
      }
#pragma unroll
      for (int n = 0; n < 4; ++n) {
        int row = wc * 64 + n * 16 + r16;
        int byte = row * 128 + ((g * 16 + kh * 64) ^ ((row & 7) << 4));
        bfr[n] = *(const bf16x8*)((const char*)Bs + byte);
      }
#pragma unroll
      for (int m = 0; m < 4; ++m)
#pragma unroll
        for (int n = 0; n < 4; ++n)
          acc[m][n] = __builtin_amdgcn_mfma_f32_16x16x32_bf16(af[m], bfr[n], acc[m][n], 0, 0, 0);
    }
    __syncthreads();
  }
#pragma unroll
  for (int m = 0; m < 4; ++m)
#pragma unroll
    for (int n = 0; n < 4; ++n)
#pragma unroll
      for (int j = 0; j < 4; ++j) {
        int row = m0 + wr * 64 + m * 16 + g * 4 + j;
        int col = n0 + wc * 64 + n * 16 + r16;
        C[(size_t)row * N + col] = acc[m][n][j];
      }
}

// ---------------- causal GQA flash attention, swapped-QK 32x32 ----------------
// NO running max: RMSNorm bounds |S_log2| <= 0.1804*96*8 ~ 17.3, so P=2^S and
// l=sum P stay in f32/bf16 range; O/l cancels the scale. Softmax per tile is
// just: mask (diag only) -> exp2 -> cvtpk/permlane -> MFMA.
__global__ __launch_bounds__(256) void k_attn2(const unsigned short* __restrict__ qn,
                                               const unsigned short* __restrict__ kn,
                                               const unsigned short* __restrict__ vt,
                                               unsigned short* __restrict__ yb) {
  __shared__ unsigned short SMEM[2 * 8192];  // 2 x (Ks 8KB | Vts 8KB) = 32KB
  const int tid = threadIdx.x;
  const int wid = tid >> 6, lane = tid & 63;
  const int hi = lane >> 5, l31 = lane & 31;
  const int flat = blockIdx.x;
  const int qx = 15 - (flat >> 6);  // longest (qx=15) blocks dispatch first
  const int bh = flat & 63;
  const int b = bh >> 4, h = bh & 15, hv = h >> 2;
  const int q0w = qx * 128 + wid * 32;
  const int qglob = q0w + l31;
  const size_t tok0 = (size_t)b * 2048;
  const unsigned short* vtb = vt + (size_t)(b * 4 + hv) * 64 * 2048;

  const u16x8 onesu = {0x3F80, 0x3F80, 0x3F80, 0x3F80, 0x3F80, 0x3F80, 0x3F80, 0x3F80};
  const bf16x8 ones = __builtin_bit_cast(bf16x8, onesu);

  bf16x8 qf[4];
#pragma unroll
  for (int m = 0; m < 4; ++m)
    qf[m] = *(const bf16x8*)(qn + (tok0 + qglob) * 1024 + h * 64 + m * 16 + hi * 8);

  f32x16 oacc[2], lacc, zer;
#pragma unroll
  for (int r = 0; r < 16; ++r) { oacc[0][r] = 0.f; oacc[1][r] = 0.f; lacc[r] = 0.f; zer[r] = 0.f; }

  const int nt = qx * 2 + 2;  // always even

  auto stage = [&](int T, int buf) {
    unsigned short* KsB = SMEM + buf * 8192;
    unsigned short* VtB = KsB + 4096;
    const int kk0 = T * 64;
#pragma unroll
    for (int c = 0; c < 2; ++c) {
      int i = wid * 2 + c;
      int row = i * 8 + (lane >> 3);
      int sc = ((lane & 7) * 16) ^ ((row & 7) << 4);
      g2l16((const char*)(kn + (tok0 + kk0 + row) * 256 + hv * 64) + sc, (char*)KsB + i * 1024);
      g2l16((const char*)(vtb + (size_t)row * 2048 + kk0) + sc, (char*)VtB + i * 1024);
    }
  };

  auto tile = [&](int t, int buf) {
    const int k0 = t * 64;
    if (t + 1 < nt) stage(t + 1, buf ^ 1);  // prefetch overlaps compute below

    if (k0 <= q0w + 31) {
      const unsigned short* KsB = SMEM + buf * 8192;
      const unsigned short* VtB = KsB + 4096;
      // ---- S^T[key][q] = K · Q^T (C chained off zero reg, no init movs) ----
      f32x16 s[2];
#pragma unroll
      for (int kt = 0; kt < 2; ++kt) {
        const int krow = kt * 32 + l31;
        const char* kbase = (const char*)KsB + krow * 128;
        const int ksw = (krow & 7) << 4;
        __builtin_amdgcn_s_setprio(1);
        bf16x8 kf = *(const bf16x8*)(kbase + ((0 * 32 + hi * 16) ^ ksw));
        f32x16 acc = __builtin_amdgcn_mfma_f32_32x32x16_bf16(kf, qf[0], zer, 0, 0, 0);
#pragma unroll
        for (int m = 1; m < 4; ++m) {
          kf = *(const bf16x8*)(kbase + ((m * 32 + hi * 16) ^ ksw));
          acc = __builtin_amdgcn_mfma_f32_32x32x16_bf16(kf, qf[m], acc, 0, 0, 0);
        }
        __builtin_amdgcn_s_setprio(0);
        s[kt] = acc;
      }
      // ---- causal mask (near-diagonal tiles only) ----
      if (k0 + 63 > q0w) {
#pragma unroll
        for (int kt = 0; kt < 2; ++kt)
#pragma unroll
          for (int r = 0; r < 16; ++r) {
            int key = k0 + kt * 32 + (r & 3) + 8 * (r >> 2) + 4 * hi;
            if (key > qglob) s[kt][r] = -INFINITY;
          }
      }
      // ---- P = exp2(S)  (exp2(-inf)=0 handles the mask) ----
#pragma unroll
      for (int kt = 0; kt < 2; ++kt)
#pragma unroll
        for (int r = 0; r < 16; ++r) s[kt][r] = exp2f(s[kt][r]);
      // ---- P -> bf16 frags via cvt_pk + permlane32_swap (T12) ----
      i32x4 paw[4];
#pragma unroll
      for (int kt = 0; kt < 2; ++kt)
#pragma unroll
        for (int half = 0; half < 2; ++half) {
          int bs = half * 8;
          unsigned int a0 = cvtpk(s[kt][bs + 0], s[kt][bs + 1]);
          unsigned int a1 = cvtpk(s[kt][bs + 2], s[kt][bs + 3]);
          unsigned int b0 = cvtpk(s[kt][bs + 4], s[kt][bs + 5]);
          unsigned int b1 = cvtpk(s[kt][bs + 6], s[kt][bs + 7]);
          i32x2 r0 = __builtin_amdgcn_permlane32_swap((int)a0, (int)b0, false, false);
          i32x2 r1 = __builtin_amdgcn_permlane32_swap((int)a1, (int)b1, false, false);
          i32x4 w;
          w[0] = r0[0]; w[1] = r1[0]; w[2] = r0[1]; w[3] = r1[1];
          paw[kt * 2 + half] = w;
        }
      // ---- O^T += V^T · P^T ; l += 1 · P^T ----
      __builtin_amdgcn_s_setprio(1);
#pragma unroll
      for (int db = 0; db < 2; ++db) {
        const int vrow = db * 32 + l31;
        const char* vbase = (const char*)VtB + vrow * 128;
        const int vsw = (vrow & 7) << 4;
#pragma unroll
        for (int ks = 0; ks < 4; ++ks) {
          bf16x8 vf = *(const bf16x8*)(vbase + ((ks * 32 + hi * 16) ^ vsw));
          oacc[db] = __builtin_amdgcn_mfma_f32_32x32x16_bf16(
              vf, __builtin_bit_cast(bf16x8, paw[ks]), oacc[db], 0, 0, 0);
        }
      }
#pragma unroll
      for (int ks = 0; ks < 4; ++ks)
        lacc = __builtin_amdgcn_mfma_f32_32x32x16_bf16(
            ones, __builtin_bit_cast(bf16x8, paw[ks]), lacc, 0, 0, 0);
      __builtin_amdgcn_s_setprio(0);
    }
    __syncthreads();  // drains prefetch (vmcnt) + protects buffer swap
  };

  stage(0, 0);
  __syncthreads();
  for (int tt = 0; tt < nt; tt += 2) {  // nt even: static buffer indices
    tile(tt, 0);
    tile(tt + 1, 1);
  }

  // ---- epilogue: O^T -> per-wave LDS transpose -> coalesced row store ----
  const float inv = 1.0f / lacc[0];
  const int swl = (l31 & 7) << 4;
  char* obase = (char*)SMEM + wid * 4096;
#pragma unroll
  for (int db = 0; db < 2; ++db)
#pragma unroll
    for (int i = 0; i < 8; ++i) {
      int r = 2 * i;
      int dim = db * 32 + (r & 3) + 8 * (r >> 2) + 4 * hi;
      unsigned int w = (unsigned int)f2bf(oacc[db][r] * inv) |
                       ((unsigned int)f2bf(oacc[db][r + 1] * inv) << 16);
      *(unsigned int*)(obase + l31 * 128 + ((dim * 2) ^ swl)) = w;
    }
  __syncthreads();
#pragma unroll
  for (int it = 0; it < 4; ++it) {
    int cc = it * 2 + hi;
    i32x4 w = *(const i32x4*)(obase + l31 * 128 + ((cc * 16) ^ swl));
    *(i32x4*)(yb + (tok0 + q0w + l31) * 1024 + h * 64 + cc * 8) = w;
  }
}

// ---------------- launch ----------------
extern "C" void kernel_launch(void* const* d_in, const int* in_sizes, int n_in,
                              void* d_out, int out_size, void* d_ws, size_t ws_size,
                              hipStream_t stream) {
  (void)in_sizes; (void)n_in; (void)out_size; (void)ws_size;
  const float* x  = (const float*)d_in[0];
  const float* Wq = (const float*)d_in[1];
  const float* Wk = (const float*)d_in[2];
  const float* Wv = (const float*)d_in[3];
  const float* Wo = (const float*)d_in[4];
  const float* qg = (const float*)d_in[5];

  char* ws = (char*)d_ws;
  unsigned short* xb   = (unsigned short*)(ws);             // 16 MB  [8192][1024]
  unsigned short* wcat = (unsigned short*)(ws + 16777216);  // 3 MB   [1536][1024]
  unsigned short* wob  = (unsigned short*)(ws + 19922944);  // 2 MB   [1024][1024]
  unsigned short* qn   = (unsigned short*)(ws + 22020096);  // 16 MB  [8192][1024]
  unsigned short* kn   = (unsigned short*)(ws + 38797312);  // 4 MB   [8192][256]
  unsigned short* yb   = xb;                                // alias: xb dead after k_qkv
  unsigned short* vt   = (unsigned short*)((char*)d_out + 25165824);  // 4 MB [16][64][2048]
  float2*         rope = (float2*)((char*)d_out + 29360128);          // 512 KB [2048][32]

  k_cvt_all<<<5632, 256, 0, stream>>>(x, Wq, Wk, Wv, Wo, xb, wcat, wob, rope);
  k_qkv<<<dim3(64, 12), 256, 0, stream>>>(xb, wcat, qg, rope, qn, kn, vt);
  k_attn2<<<1024, 256, 0, stream>>>(qn, kn, vt, yb);
  k_gemm_bt<<<dim3(64, 8), 256, 0, stream>>>(yb, wob, (float*)d_out, 8192, 1024, 1024);
}

// Round 10
// 151.944 us; speedup vs baseline: 1.5358x; 1.0172x over previous
//
#include <hip/hip_runtime.h>

typedef float f32x4 __attribute__((ext_vector_type(4)));
typedef float f32x16 __attribute__((ext_vector_type(16)));
typedef __bf16 bf16x8 __attribute__((ext_vector_type(8)));
typedef unsigned short u16x8 __attribute__((ext_vector_type(8)));
typedef int i32x2 __attribute__((ext_vector_type(2)));
typedef int i32x4 __attribute__((ext_vector_type(4)));

#define DEV static __device__ __forceinline__

DEV float bf2f(unsigned short h) {
  unsigned int u = ((unsigned int)h) << 16;
  return __builtin_bit_cast(float, u);
}
DEV unsigned short f2bf(float f) {
  unsigned int u = __builtin_bit_cast(unsigned int, f);
  u += 0x7fff + ((u >> 16) & 1);   // RTNE
  return (unsigned short)(u >> 16);
}

DEV void g2l16(const void* g, void* l) {
  __builtin_amdgcn_global_load_lds(
      (const __attribute__((address_space(1))) void*)g,
      (__attribute__((address_space(3))) void*)l, 16, 0, 0);
}

DEV unsigned int cvtpk(float lo, float hi) {
  unsigned int r;
  asm("v_cvt_pk_bf16_f32 %0, %1, %2" : "=v"(r) : "v"(lo), "v"(hi));
  return r;
}

// ---------------- fused converts + RoPE table ----------------
DEV void cvt8(const float* __restrict__ in, unsigned short* __restrict__ out, int idx) {
  int i = idx * 8;
  float4 a = *(const float4*)(in + i);
  float4 b = *(const float4*)(in + i + 4);
  u16x8 r;
  r[0] = f2bf(a.x); r[1] = f2bf(a.y); r[2] = f2bf(a.z); r[3] = f2bf(a.w);
  r[4] = f2bf(b.x); r[5] = f2bf(b.y); r[6] = f2bf(b.z); r[7] = f2bf(b.w);
  *(u16x8*)(out + i) = r;
}

__global__ __launch_bounds__(256) void k_cvt_all(const float* __restrict__ x,
                                                 const float* __restrict__ wq,
                                                 const float* __restrict__ wk,
                                                 const float* __restrict__ wv,
                                                 const float* __restrict__ wo,
                                                 unsigned short* __restrict__ xb,
                                                 unsigned short* __restrict__ wcat,
                                                 unsigned short* __restrict__ wob,
                                                 float2* __restrict__ rope) {
  const int blk = blockIdx.x, tid = threadIdx.x;
  if (blk < 4096) {
    cvt8(x, xb, blk * 256 + tid);
  } else if (blk < 4608) {
    cvt8(wq, wcat, (blk - 4096) * 256 + tid);
  } else if (blk < 4736) {
    cvt8(wk, wcat + 1048576, (blk - 4608) * 256 + tid);
  } else if (blk < 4864) {
    cvt8(wv, wcat + 1310720, (blk - 4736) * 256 + tid);
  } else if (blk < 5376) {
    cvt8(wo, wob, (blk - 4864) * 256 + tid);
  } else {
    int idx = (blk - 5376) * 256 + tid;   // [0, 65536)
    int s = idx >> 5, dmod = idx & 31;
    float inv_freq = powf(10000.0f, -(float)dmod * (1.0f / 32.0f));
    float sn, cs;
    sincosf((float)s * inv_freq, &sn, &cs);
    rope[idx] = make_float2(cs, sn);
  }
}

// ---------------- fused QKV GEMM + RMSNorm/RoPE/gain + V-transpose ----------------
__global__ __launch_bounds__(256) void k_qkv(const unsigned short* __restrict__ A,
                                             const unsigned short* __restrict__ B,
                                             const float* __restrict__ qg,
                                             const float2* __restrict__ rope,
                                             unsigned short* __restrict__ qn,
                                             unsigned short* __restrict__ kn,
                                             unsigned short* __restrict__ vt) {
  __shared__ unsigned short LDS[16384];
  unsigned short* As = LDS;
  unsigned short* Bs = LDS + 8192;
  const int K = 1024;
  const int tid = threadIdx.x;
  const int wid = tid >> 6, lane = tid & 63;
  const int g = lane >> 4, r16 = lane & 15;
  const int m0 = blockIdx.x * 128;
  const int y = blockIdx.y;
  const int n0 = y * 128;
  const int wr = wid >> 1, wc = wid & 1;

  f32x4 acc[4][4];
#pragma unroll
  for (int i = 0; i < 4; ++i)
#pragma unroll
    for (int j = 0; j < 4; ++j) acc[i][j] = f32x4{0.f, 0.f, 0.f, 0.f};

  const int cb = (lane & 7) * 16;

  for (int k0 = 0; k0 < K; k0 += 64) {
#pragma unroll
    for (int c = 0; c < 4; ++c) {
      int i = wid * 4 + c;
      int row = i * 8 + (lane >> 3);
      int sc = cb ^ ((row & 7) << 4);
      g2l16((const char*)A + ((size_t)(m0 + row) * K + k0) * 2 + sc, (char*)As + i * 1024);
      g2l16((const char*)B + ((size_t)(n0 + row) * K + k0) * 2 + sc, (char*)Bs + i * 1024);
    }
    __syncthreads();
#pragma unroll
    for (int kh = 0; kh < 2; ++kh) {
      bf16x8 af[4], bfr[4];
#pragma unroll
      for (int m = 0; m < 4; ++m) {
        int row = wr * 64 + m * 16 + r16;
        int byte = row * 128 + ((g * 16 + kh * 64) ^ ((row & 7) << 4));
        af[m] = *(const bf16x8*)((const char*)As + byte);
      }
#pragma unroll
      for (int n = 0; n < 4; ++n) {
        int row = wc * 64 + n * 16 + r16;
        int byte = row * 128 + ((g * 16 + kh * 64) ^ ((row & 7) << 4));
        bfr[n] = *(const bf16x8*)((const char*)Bs + byte);
      }
#pragma unroll
      for (int m = 0; m < 4; ++m)
#pragma unroll
        for (int n = 0; n < 4; ++n)
          acc[m][n] = __builtin_amdgcn_mfma_f32_16x16x32_bf16(af[m], bfr[n], acc[m][n], 0, 0, 0);
    }
    __syncthreads();
  }

  if (y < 10) {
    const bool isq = (y < 8);
    const int head = isq ? (2 * y + wc) : (2 * (y - 8) + wc);
    const float gain = isq ? qg[head] * 0.18033688011112042f : 1.0f;  // fold 1/8*log2e into q
#pragma unroll
    for (int m = 0; m < 4; ++m)
#pragma unroll
      for (int j = 0; j < 4; ++j) {
        int rowl = wr * 64 + m * 16 + g * 4 + j;
        int tok = m0 + rowl;
        int s = tok & 2047;
        float v0 = acc[m][0][j], v1 = acc[m][1][j], v2 = acc[m][2][j], v3 = acc[m][3][j];
        float ss = v0 * v0 + v1 * v1 + v2 * v2 + v3 * v3;
        ss += __shfl_xor(ss, 1); ss += __shfl_xor(ss, 2);
        ss += __shfl_xor(ss, 4); ss += __shfl_xor(ss, 8);
        float rs = rsqrtf(ss * (1.0f / 64.0f) + 1e-6f) * gain;
        float2 cs0 = rope[s * 32 + r16];
        float2 cs1 = rope[s * 32 + 16 + r16];
        float o0 = (v0 * cs0.x + v2 * cs0.y) * rs;
        float o2 = (v2 * cs0.x - v0 * cs0.y) * rs;
        float o1 = (v1 * cs1.x + v3 * cs1.y) * rs;
        float o3 = (v3 * cs1.x - v1 * cs1.y) * rs;
        unsigned short* dst = isq ? (qn + (size_t)tok * 1024 + head * 64)
                                  : (kn + (size_t)tok * 256 + head * 64);
        dst[r16] = f2bf(o0);
        dst[16 + r16] = f2bf(o1);
        dst[32 + r16] = f2bf(o2);
        dst[48 + r16] = f2bf(o3);
      }
  } else {
    unsigned short* T = LDS;
#pragma unroll
    for (int m = 0; m < 4; ++m)
#pragma unroll
      for (int n = 0; n < 4; ++n)
#pragma unroll
        for (int j = 0; j < 4; ++j) {
          int tokl = wr * 64 + m * 16 + g * 4 + j;
          int dl = wc * 64 + n * 16 + r16;
          int byte = (dl * 256 + tokl * 2) ^ ((dl & 15) << 4);
          *(unsigned short*)((char*)T + byte) = f2bf(acc[m][n][j]);
        }
    __syncthreads();
    const int d = tid >> 1, th = tid & 1;
    const int hv = 2 * (y - 10) + (d >> 6), dh = d & 63;
    const int bb = m0 >> 11;
    const int s0 = (m0 & 2047) + th * 64;
    unsigned short* dstv = vt + ((size_t)(bb * 4 + hv) * 64 + dh) * 2048 + s0;
    const int swz = (d & 15) << 4;
#pragma unroll
    for (int c = 0; c < 8; ++c) {
      i32x4 w = *(const i32x4*)((const char*)T + ((d * 256 + th * 128 + c * 16) ^ swz));
      *(i32x4*)(dstv + c * 8) = w;
    }
  }
}

// ---------------- NT GEMM (m97) for out-proj ----------------
__global__ __launch_bounds__(256) void k_gemm_bt(const unsigned short* __restrict__ A,
                                                 const unsigned short* __restrict__ B,
                                                 float* __restrict__ C, int M, int N, int K) {
  __shared__ unsigned short As[128 * 64];
  __shared__ unsigned short Bs[128 * 64];
  const int tid = threadIdx.x;
  const int wid = tid >> 6, lane = tid & 63;
  const int g = lane >> 4, r16 = lane & 15;
  const int m0 = blockIdx.x * 128, n0 = blockIdx.y * 128;
  const int wr = wid >> 1, wc = wid & 1;

  f32x4 acc[4][4];
#pragma unroll
  for (int i = 0; i < 4; ++i)
#pragma unroll
    for (int j = 0; j < 4; ++j) acc[i][j] = f32x4{0.f, 0.f, 0.f, 0.f};

  const int cb = (lane & 7) * 16;

  for (int k0 = 0; k0 < K; k0 += 64) {
#pragma unroll
    for (int c = 0; c < 4; ++c) {
      int i = wid * 4 + c;
      int row = i * 8 + (lane >> 3);
      int sc = cb ^ ((row & 7) << 4);
      g2l16((const char*)A + ((size_t)(m0 + row) * K + k0) * 2 + sc, (char*)As + i * 1024);
      g2l16((const char*)B + ((size_t)(n0 + row) * K + k0) * 2 + sc, (char*)Bs + i * 1024);
    }
    __syncthreads();
#pragma unroll
    for (int kh = 0; kh < 2; ++kh) {
      bf16x8 af[4], bfr[4];
#pragma unroll
      for (int m = 0; m < 4; ++m) {
        int row = wr * 64 + m * 16 + r16;
        int byte = row * 128 + ((g * 16 + kh * 64) ^ ((row & 7) << 4));
        af[m] = *(const bf16x8*)((const char*)As + byte);
      }
#pragma unroll
      for (int n = 0; n < 4; ++n) {
        int row = wc * 64 + n * 16 + r16;
        int byte = row * 128 + ((g * 16 + kh * 64) ^ ((row & 7) << 4));
        bfr[n] = *(const bf16x8*)((const char*)Bs + byte);
      }
#pragma unroll
      for (int m = 0; m < 4; ++m)
#pragma unroll
        for (int n = 0; n < 4; ++n)
          acc[m][n] = __builtin_amdgcn_mfma_f32_16x16x32_bf16(af[m], bfr[n], acc[m][n], 0, 0, 0);
    }
    __syncthreads();
  }
#pragma unroll
  for (int m = 0; m < 4; ++m)
#pragma unroll
    for (int n = 0; n < 4; ++n)
#pragma unroll
      for (int j = 0; j < 4; ++j) {
        int row = m0 + wr * 64 + m * 16 + g * 4 + j;
        int col = n0 + wc * 64 + n * 16 + r16;
        C[(size_t)row * N + col] = acc[m][n][j];
      }
}

// ---------------- causal GQA flash attention, swapped-QK 32x32, pair-pipelined ----------------
// Max-free softmax (RMSNorm bounds S). 4 tile-buffers (64KB LDS), pair-level
// double-buffer: one barrier per 2 tiles; pair body is straight-line
// QK(t);QK(t+1);exp(t);PV(t);exp(t+1);PV(t+1) so exp/cvt (VALU/trans) hides
// under MFMA of the neighboring tile (T15 mechanism). Mask only in final pair.
__global__ __launch_bounds__(256) void k_attn2(const unsigned short* __restrict__ qn,
                                               const unsigned short* __restrict__ kn,
                                               const unsigned short* __restrict__ vt,
                                               unsigned short* __restrict__ yb) {
  __shared__ unsigned short SMEM[4 * 8192];  // 4 tile-bufs x (Ks 8KB | Vts 8KB) = 64KB
  const int tid = threadIdx.x;
  const int wid = tid >> 6, lane = tid & 63;
  const int hi = lane >> 5, l31 = lane & 31;
  const int flat = blockIdx.x;
  const int qx = 15 - (flat >> 6);  // longest (qx=15) blocks dispatch first
  const int bh = flat & 63;
  const int b = bh >> 4, h = bh & 15, hv = h >> 2;
  const int q0w = qx * 128 + wid * 32;
  const int qglob = q0w + l31;
  const size_t tok0 = (size_t)b * 2048;
  const unsigned short* vtb = vt + (size_t)(b * 4 + hv) * 64 * 2048;

  const u16x8 onesu = {0x3F80, 0x3F80, 0x3F80, 0x3F80, 0x3F80, 0x3F80, 0x3F80, 0x3F80};
  const bf16x8 ones = __builtin_bit_cast(bf16x8, onesu);

  bf16x8 qf[4];
#pragma unroll
  for (int m = 0; m < 4; ++m)
    qf[m] = *(const bf16x8*)(qn + (tok0 + qglob) * 1024 + h * 64 + m * 16 + hi * 8);

  f32x16 oacc[2], lacc, zer;
#pragma unroll
  for (int r = 0; r < 16; ++r) { oacc[0][r] = 0.f; oacc[1][r] = 0.f; lacc[r] = 0.f; zer[r] = 0.f; }

  auto stage = [&](int T, int tb) {
    unsigned short* KsB = SMEM + tb * 8192;
    unsigned short* VtB = KsB + 4096;
    const int kk0 = T * 64;
#pragma unroll
    for (int c = 0; c < 2; ++c) {
      int i = wid * 2 + c;
      int row = i * 8 + (lane >> 3);
      int sc = ((lane & 7) * 16) ^ ((row & 7) << 4);
      g2l16((const char*)(kn + (tok0 + kk0 + row) * 256 + hv * 64) + sc, (char*)KsB + i * 1024);
      g2l16((const char*)(vtb + (size_t)row * 2048 + kk0) + sc, (char*)VtB + i * 1024);
    }
  };

  auto qk_tile = [&](int tb, f32x16* s) {
    const char* kbase0 = (const char*)SMEM + tb * 16384;
#pragma unroll
    for (int kt = 0; kt < 2; ++kt) {
      const int krow = kt * 32 + l31;
      const char* kbase = kbase0 + krow * 128;
      const int ksw = (krow & 7) << 4;
      __builtin_amdgcn_s_setprio(1);
      bf16x8 kf = *(const bf16x8*)(kbase + ((hi * 16) ^ ksw));
      f32x16 a = __builtin_amdgcn_mfma_f32_32x32x16_bf16(kf, qf[0], zer, 0, 0, 0);
#pragma unroll
      for (int m = 1; m < 4; ++m) {
        kf = *(const bf16x8*)(kbase + ((m * 32 + hi * 16) ^ ksw));
        a = __builtin_amdgcn_mfma_f32_32x32x16_bf16(kf, qf[m], a, 0, 0, 0);
      }
      __builtin_amdgcn_s_setprio(0);
      s[kt] = a;
    }
  };

  auto mask_tile = [&](int t, f32x16* s) {
    const int k0 = t * 64;
#pragma unroll
    for (int kt = 0; kt < 2; ++kt)
#pragma unroll
      for (int r = 0; r < 16; ++r) {
        int key = k0 + kt * 32 + (r & 3) + 8 * (r >> 2) + 4 * hi;
        if (key > qglob) s[kt][r] = -INFINITY;
      }
  };

  auto softmax_cvt = [&](f32x16* s, i32x4* paw) {
#pragma unroll
    for (int kt = 0; kt < 2; ++kt)
#pragma unroll
      for (int r = 0; r < 16; ++r) s[kt][r] = exp2f(s[kt][r]);
#pragma unroll
    for (int kt = 0; kt < 2; ++kt)
#pragma unroll
      for (int half = 0; half < 2; ++half) {
        int bs = half * 8;
        unsigned int a0 = cvtpk(s[kt][bs + 0], s[kt][bs + 1]);
        unsigned int a1 = cvtpk(s[kt][bs + 2], s[kt][bs + 3]);
        unsigned int b0 = cvtpk(s[kt][bs + 4], s[kt][bs + 5]);
        unsigned int b1 = cvtpk(s[kt][bs + 6], s[kt][bs + 7]);
        i32x2 r0 = __builtin_amdgcn_permlane32_swap((int)a0, (int)b0, false, false);
        i32x2 r1 = __builtin_amdgcn_permlane32_swap((int)a1, (int)b1, false, false);
        i32x4 w;
        w[0] = r0[0]; w[1] = r1[0]; w[2] = r0[1]; w[3] = r1[1];
        paw[kt * 2 + half] = w;
      }
  };

  auto pv_tile = [&](int tb, const i32x4* paw) {
    const char* vbase0 = (const char*)SMEM + tb * 16384 + 8192;
    __builtin_amdgcn_s_setprio(1);
#pragma unroll
    for (int db = 0; db < 2; ++db) {
      const int vrow = db * 32 + l31;
      const char* vbase = vbase0 + vrow * 128;
      const int vsw = (vrow & 7) << 4;
#pragma unroll
      for (int ks = 0; ks < 4; ++ks) {
        bf16x8 vf = *(const bf16x8*)(vbase + ((ks * 32 + hi * 16) ^ vsw));
        oacc[db] = __builtin_amdgcn_mfma_f32_32x32x16_bf16(
            vf, __builtin_bit_cast(bf16x8, paw[ks]), oacc[db], 0, 0, 0);
      }
    }
#pragma unroll
    for (int ks = 0; ks < 4; ++ks)
      lacc = __builtin_amdgcn_mfma_f32_32x32x16_bf16(
          ones, __builtin_bit_cast(bf16x8, paw[ks]), lacc, 0, 0, 0);
    __builtin_amdgcn_s_setprio(0);
  };

  const int npair = qx + 1;

  stage(0, 0);
  stage(1, 1);
  __syncthreads();

  for (int p = 0; p < npair - 1; ++p) {
    const int pb = (p & 1) << 1;   // tile-bufs pb, pb|1
    const int nb = pb ^ 2;
    stage(2 * p + 2, nb);
    stage(2 * p + 3, nb | 1);
    f32x16 sa[2], sb[2];
    qk_tile(pb, sa);
    qk_tile(pb | 1, sb);
    i32x4 pawa[4], pawb[4];
    softmax_cvt(sa, pawa);      // overlaps qk_tile(pb|1) MFMAs
    pv_tile(pb, pawa);
    softmax_cvt(sb, pawb);      // overlaps pv_tile(pb) MFMAs
    pv_tile(pb | 1, pawb);
    __syncthreads();            // drains prefetch + frees bufs pb,pb|1
  }
  {
    const int p = npair - 1;
    const int pb = (p & 1) << 1;
    const int t0 = 2 * p;
    f32x16 sa[2], sb[2];
    qk_tile(pb, sa);
    qk_tile(pb | 1, sb);
    mask_tile(t0, sa);
    mask_tile(t0 + 1, sb);
    i32x4 pawa[4], pawb[4];
    softmax_cvt(sa, pawa);
    pv_tile(pb, pawa);
    softmax_cvt(sb, pawb);
    pv_tile(pb | 1, pawb);
    __syncthreads();            // all waves done with K/V before LDS reuse below
  }

  // ---- epilogue: O^T -> per-wave LDS transpose -> coalesced row store ----
  const float inv = 1.0f / lacc[0];
  const int swl = (l31 & 7) << 4;
  char* obase = (char*)SMEM + wid * 4096;
#pragma unroll
  for (int db = 0; db < 2; ++db)
#pragma unroll
    for (int i = 0; i < 8; ++i) {
      int r = 2 * i;
      int dim = db * 32 + (r & 3) + 8 * (r >> 2) + 4 * hi;
      unsigned int w = (unsigned int)f2bf(oacc[db][r] * inv) |
                       ((unsigned int)f2bf(oacc[db][r + 1] * inv) << 16);
      *(unsigned int*)(obase + l31 * 128 + ((dim * 2) ^ swl)) = w;
    }
  __syncthreads();
#pragma unroll
  for (int it = 0; it < 4; ++it) {
    int cc = it * 2 + hi;
    i32x4 w = *(const i32x4*)(obase + l31 * 128 + ((cc * 16) ^ swl));
    *(i32x4*)(yb + (tok0 + q0w + l31) * 1024 + h * 64 + cc * 8) = w;
  }
}

// ---------------- launch ----------------
extern "C" void kernel_launch(void* const* d_in, const int* in_sizes, int n_in,
                              void* d_out, int out_size, void* d_ws, size_t ws_size,
                              hipStream_t stream) {
  (void)in_sizes; (void)n_in; (void)out_size; (void)ws_size;
  const float* x  = (const float*)d_in[0];
  const float* Wq = (const float*)d_in[1];
  const float* Wk = (const float*)d_in[2];
  const float* Wv = (const float*)d_in[3];
  const float* Wo = (const float*)d_in[4];
  const float* qg = (const float*)d_in[5];

  char* ws = (char*)d_ws;
  unsigned short* xb   = (unsigned short*)(ws);             // 16 MB  [8192][1024]
  unsigned short* wcat = (unsigned short*)(ws + 16777216);  // 3 MB   [1536][1024]
  unsigned short* wob  = (unsigned short*)(ws + 19922944);  // 2 MB   [1024][1024]
  unsigned short* qn   = (unsigned short*)(ws + 22020096);  // 16 MB  [8192][1024]
  unsigned short* kn   = (unsigned short*)(ws + 38797312);  // 4 MB   [8192][256]
  unsigned short* yb   = xb;                                // alias: xb dead after k_qkv
  unsigned short* vt   = (unsigned short*)((char*)d_out + 25165824);  // 4 MB [16][64][2048]
  float2*         rope = (float2*)((char*)d_out + 29360128);          // 512 KB [2048][32]

  k_cvt_all<<<5632, 256, 0, stream>>>(x, Wq, Wk, Wv, Wo, xb, wcat, wob, rope);
  k_qkv<<<dim3(64, 12), 256, 0, stream>>>(xb, wcat, qg, rope, qn, kn, vt);
  k_attn2<<<1024, 256, 0, stream>>>(qn, kn, vt, yb);
  k_gemm_bt<<<dim3(64, 8), 256, 0, stream>>>(yb, wob, (float*)d_out, 8192, 1024, 1024);
}

// Round 11
// 134.218 us; speedup vs baseline: 1.7386x; 1.1321x over previous
//
#include <hip/hip_runtime.h>

typedef float f32x4 __attribute__((ext_vector_type(4)));
typedef float f32x16 __attribute__((ext_vector_type(16)));
typedef __bf16 bf16x8 __attribute__((ext_vector_type(8)));
typedef unsigned short u16x8 __attribute__((ext_vector_type(8)));
typedef int i32x2 __attribute__((ext_vector_type(2)));
typedef int i32x4 __attribute__((ext_vector_type(4)));

#define DEV static __device__ __forceinline__

DEV float bf2f(unsigned short h) {
  unsigned int u = ((unsigned int)h) << 16;
  return __builtin_bit_cast(float, u);
}
DEV unsigned short f2bf(float f) {
  unsigned int u = __builtin_bit_cast(unsigned int, f);
  u += 0x7fff + ((u >> 16) & 1);   // RTNE
  return (unsigned short)(u >> 16);
}

DEV void g2l16(const void* g, void* l) {
  __builtin_amdgcn_global_load_lds(
      (const __attribute__((address_space(1))) void*)g,
      (__attribute__((address_space(3))) void*)l, 16, 0, 0);
}

DEV unsigned int cvtpk(float lo, float hi) {
  unsigned int r;
  asm("v_cvt_pk_bf16_f32 %0, %1, %2" : "=v"(r) : "v"(lo), "v"(hi));
  return r;
}

// raw hardware exp2: |S| bounded (<18) so no libm range fixups needed;
// v_exp_f32(-inf) = 0 handles masked entries.
DEV float fexp2(float x) {
  float r;
  asm("v_exp_f32 %0, %1" : "=v"(r) : "v"(x));
  return r;
}

// ---------------- fused converts + RoPE table ----------------
DEV void cvt8(const float* __restrict__ in, unsigned short* __restrict__ out, int idx) {
  int i = idx * 8;
  float4 a = *(const float4*)(in + i);
  float4 b = *(const float4*)(in + i + 4);
  u16x8 r;
  r[0] = f2bf(a.x); r[1] = f2bf(a.y); r[2] = f2bf(a.z); r[3] = f2bf(a.w);
  r[4] = f2bf(b.x); r[5] = f2bf(b.y); r[6] = f2bf(b.z); r[7] = f2bf(b.w);
  *(u16x8*)(out + i) = r;
}

__global__ __launch_bounds__(256) void k_cvt_all(const float* __restrict__ x,
                                                 const float* __restrict__ wq,
                                                 const float* __restrict__ wk,
                                                 const float* __restrict__ wv,
                                                 const float* __restrict__ wo,
                                                 unsigned short* __restrict__ xb,
                                                 unsigned short* __restrict__ wcat,
                                                 unsigned short* __restrict__ wob,
                                                 float2* __restrict__ rope) {
  const int blk = blockIdx.x, tid = threadIdx.x;
  if (blk < 4096) {
    cvt8(x, xb, blk * 256 + tid);
  } else if (blk < 4608) {
    cvt8(wq, wcat, (blk - 4096) * 256 + tid);
  } else if (blk < 4736) {
    cvt8(wk, wcat + 1048576, (blk - 4608) * 256 + tid);
  } else if (blk < 4864) {
    cvt8(wv, wcat + 1310720, (blk - 4736) * 256 + tid);
  } else if (blk < 5376) {
    cvt8(wo, wob, (blk - 4864) * 256 + tid);
  } else {
    int idx = (blk - 5376) * 256 + tid;   // [0, 65536)
    int s = idx >> 5, dmod = idx & 31;
    float inv_freq = powf(10000.0f, -(float)dmod * (1.0f / 32.0f));
    float sn, cs;
    sincosf((float)s * inv_freq, &sn, &cs);
    rope[idx] = make_float2(cs, sn);
  }
}

// ---------------- fused QKV GEMM + RMSNorm/RoPE/gain + V-transpose ----------------
__global__ __launch_bounds__(256) void k_qkv(const unsigned short* __restrict__ A,
                                             const unsigned short* __restrict__ B,
                                             const float* __restrict__ qg,
                                             const float2* __restrict__ rope,
                                             unsigned short* __restrict__ qn,
                                             unsigned short* __restrict__ kn,
                                             unsigned short* __restrict__ vt) {
  __shared__ unsigned short LDS[16384];
  unsigned short* As = LDS;
  unsigned short* Bs = LDS + 8192;
  const int K = 1024;
  const int tid = threadIdx.x;
  const int wid = tid >> 6, lane = tid & 63;
  const int g = lane >> 4, r16 = lane & 15;
  const int m0 = blockIdx.x * 128;
  const int y = blockIdx.y;
  const int n0 = y * 128;
  const int wr = wid >> 1, wc = wid & 1;

  f32x4 acc[4][4];
#pragma unroll
  for (int i = 0; i < 4; ++i)
#pragma unroll
    for (int j = 0; j < 4; ++j) acc[i][j] = f32x4{0.f, 0.f, 0.f, 0.f};

  const int cb = (lane & 7) * 16;

  for (int k0 = 0; k0 < K; k0 += 64) {
#pragma unroll
    for (int c = 0; c < 4; ++c) {
      int i = wid * 4 + c;
      int row = i * 8 + (lane >> 3);
      int sc = cb ^ ((row & 7) << 4);
      g2l16((const char*)A + ((size_t)(m0 + row) * K + k0) * 2 + sc, (char*)As + i * 1024);
      g2l16((const char*)B + ((size_t)(n0 + row) * K + k0) * 2 + sc, (char*)Bs + i * 1024);
    }
    __syncthreads();
#pragma unroll
    for (int kh = 0; kh < 2; ++kh) {
      bf16x8 af[4], bfr[4];
#pragma unroll
      for (int m = 0; m < 4; ++m) {
        int row = wr * 64 + m * 16 + r16;
        int byte = row * 128 + ((g * 16 + kh * 64) ^ ((row & 7) << 4));
        af[m] = *(const bf16x8*)((const char*)As + byte);
      }
#pragma unroll
      for (int n = 0; n < 4; ++n) {
        int row = wc * 64 + n * 16 + r16;
        int byte = row * 128 + ((g * 16 + kh * 64) ^ ((row & 7) << 4));
        bfr[n] = *(const bf16x8*)((const char*)Bs + byte);
      }
#pragma unroll
      for (int m = 0; m < 4; ++m)
#pragma unroll
        for (int n = 0; n < 4; ++n)
          acc[m][n] = __builtin_amdgcn_mfma_f32_16x16x32_bf16(af[m], bfr[n], acc[m][n], 0, 0, 0);
    }
    __syncthreads();
  }

  if (y < 10) {
    const bool isq = (y < 8);
    const int head = isq ? (2 * y + wc) : (2 * (y - 8) + wc);
    const float gain = isq ? qg[head] * 0.18033688011112042f : 1.0f;  // fold 1/8*log2e into q
#pragma unroll
    for (int m = 0; m < 4; ++m)
#pragma unroll
      for (int j = 0; j < 4; ++j) {
        int rowl = wr * 64 + m * 16 + g * 4 + j;
        int tok = m0 + rowl;
        int s = tok & 2047;
        float v0 = acc[m][0][j], v1 = acc[m][1][j], v2 = acc[m][2][j], v3 = acc[m][3][j];
        float ss = v0 * v0 + v1 * v1 + v2 * v2 + v3 * v3;
        ss += __shfl_xor(ss, 1); ss += __shfl_xor(ss, 2);
        ss += __shfl_xor(ss, 4); ss += __shfl_xor(ss, 8);
        float rs = rsqrtf(ss * (1.0f / 64.0f) + 1e-6f) * gain;
        float2 cs0 = rope[s * 32 + r16];
        float2 cs1 = rope[s * 32 + 16 + r16];
        float o0 = (v0 * cs0.x + v2 * cs0.y) * rs;
        float o2 = (v2 * cs0.x - v0 * cs0.y) * rs;
        float o1 = (v1 * cs1.x + v3 * cs1.y) * rs;
        float o3 = (v3 * cs1.x - v1 * cs1.y) * rs;
        unsigned short* dst = isq ? (qn + (size_t)tok * 1024 + head * 64)
                                  : (kn + (size_t)tok * 256 + head * 64);
        dst[r16] = f2bf(o0);
        dst[16 + r16] = f2bf(o1);
        dst[32 + r16] = f2bf(o2);
        dst[48 + r16] = f2bf(o3);
      }
  } else {
    unsigned short* T = LDS;
#pragma unroll
    for (int m = 0; m < 4; ++m)
#pragma unroll
      for (int n = 0; n < 4; ++n)
#pragma unroll
        for (int j = 0; j < 4; ++j) {
          int tokl = wr * 64 + m * 16 + g * 4 + j;
          int dl = wc * 64 + n * 16 + r16;
          int byte = (dl * 256 + tokl * 2) ^ ((dl & 15) << 4);
          *(unsigned short*)((char*)T + byte) = f2bf(acc[m][n][j]);
        }
    __syncthreads();
    const int d = tid >> 1, th = tid & 1;
    const int hv = 2 * (y - 10) + (d >> 6), dh = d & 63;
    const int bb = m0 >> 11;
    const int s0 = (m0 & 2047) + th * 64;
    unsigned short* dstv = vt + ((size_t)(bb * 4 + hv) * 64 + dh) * 2048 + s0;
    const int swz = (d & 15) << 4;
#pragma unroll
    for (int c = 0; c < 8; ++c) {
      i32x4 w = *(const i32x4*)((const char*)T + ((d * 256 + th * 128 + c * 16) ^ swz));
      *(i32x4*)(dstv + c * 8) = w;
    }
  }
}

// ---------------- NT GEMM (m97) for out-proj ----------------
__global__ __launch_bounds__(256) void k_gemm_bt(const unsigned short* __restrict__ A,
                                                 const unsigned short* __restrict__ B,
                                                 float* __restrict__ C, int M, int N, int K) {
  __shared__ unsigned short As[128 * 64];
  __shared__ unsigned short Bs[128 * 64];
  const int tid = threadIdx.x;
  const int wid = tid >> 6, lane = tid & 63;
  const int g = lane >> 4, r16 = lane & 15;
  const int m0 = blockIdx.x * 128, n0 = blockIdx.y * 128;
  const int wr = wid >> 1, wc = wid & 1;

  f32x4 acc[4][4];
#pragma unroll
  for (int i = 0; i < 4; ++i)
#pragma unroll
    for (int j = 0; j < 4; ++j) acc[i][j] = f32x4{0.f, 0.f, 0.f, 0.f};

  const int cb = (lane & 7) * 16;

  for (int k0 = 0; k0 < K; k0 += 64) {
#pragma unroll
    for (int c = 0; c < 4; ++c) {
      int i = wid * 4 + c;
      int row = i * 8 + (lane >> 3);
      int sc = cb ^ ((row & 7) << 4);
      g2l16((const char*)A + ((size_t)(m0 + row) * K + k0) * 2 + sc, (char*)As + i * 1024);
      g2l16((const char*)B + ((size_t)(n0 + row) * K + k0) * 2 + sc, (char*)Bs + i * 1024);
    }
    __syncthreads();
#pragma unroll
    for (int kh = 0; kh < 2; ++kh) {
      bf16x8 af[4], bfr[4];
#pragma unroll
      for (int m = 0; m < 4; ++m) {
        int row = wr * 64 + m * 16 + r16;
        int byte = row * 128 + ((g * 16 + kh * 64) ^ ((row & 7) << 4));
        af[m] = *(const bf16x8*)((const char*)As + byte);
      }
#pragma unroll
      for (int n = 0; n < 4; ++n) {
        int row = wc * 64 + n * 16 + r16;
        int byte = row * 128 + ((g * 16 + kh * 64) ^ ((row & 7) << 4));
        bfr[n] = *(const bf16x8*)((const char*)Bs + byte);
      }
#pragma unroll
      for (int m = 0; m < 4; ++m)
#pragma unroll
        for (int n = 0; n < 4; ++n)
          acc[m][n] = __builtin_amdgcn_mfma_f32_16x16x32_bf16(af[m], bfr[n], acc[m][n], 0, 0, 0);
    }
    __syncthreads();
  }
#pragma unroll
  for (int m = 0; m < 4; ++m)
#pragma unroll
    for (int n = 0; n < 4; ++n)
#pragma unroll
      for (int j = 0; j < 4; ++j) {
        int row = m0 + wr * 64 + m * 16 + g * 4 + j;
        int col = n0 + wc * 64 + n * 16 + r16;
        C[(size_t)row * N + col] = acc[m][n][j];
      }
}

// ---------------- causal GQA flash attention, swapped-QK 32x32, 8-wave pair-pipelined ----
// Max-free softmax. 8 waves x 32 q-rows = 256 q-rows/block, grid 512 (desc).
// 4 tile-bufs (64KB LDS) -> 2 blocks/CU = 4 waves/SIMD. Raw v_exp_f32.
// Mask applied in the last two pairs (covers every wave's diagonal tile).
__global__ __launch_bounds__(512) void k_attn2(const unsigned short* __restrict__ qn,
                                               const unsigned short* __restrict__ kn,
                                               const unsigned short* __restrict__ vt,
                                               unsigned short* __restrict__ yb) {
  __shared__ unsigned short SMEM[4 * 8192];  // 4 tile-bufs x (Ks 8KB | Vts 8KB) = 64KB
  const int tid = threadIdx.x;
  const int wid = tid >> 6, lane = tid & 63;
  const int hi = lane >> 5, l31 = lane & 31;
  const int flat = blockIdx.x;
  const int qcx = 7 - (flat >> 6);  // longest blocks dispatch first
  const int bh = flat & 63;
  const int b = bh >> 4, h = bh & 15, hv = h >> 2;
  const int q0w = qcx * 256 + wid * 32;
  const int qglob = q0w + l31;
  const int tdiag = (q0w + 31) >> 6;  // wave's diagonal tile
  const size_t tok0 = (size_t)b * 2048;
  const unsigned short* vtb = vt + (size_t)(b * 4 + hv) * 64 * 2048;

  const u16x8 onesu = {0x3F80, 0x3F80, 0x3F80, 0x3F80, 0x3F80, 0x3F80, 0x3F80, 0x3F80};
  const bf16x8 ones = __builtin_bit_cast(bf16x8, onesu);

  bf16x8 qf[4];
#pragma unroll
  for (int m = 0; m < 4; ++m)
    qf[m] = *(const bf16x8*)(qn + (tok0 + qglob) * 1024 + h * 64 + m * 16 + hi * 8);

  f32x16 oacc[2], lacc, zer;
#pragma unroll
  for (int r = 0; r < 16; ++r) { oacc[0][r] = 0.f; oacc[1][r] = 0.f; lacc[r] = 0.f; zer[r] = 0.f; }

  auto stage = [&](int T, int tb) {
    unsigned short* KsB = SMEM + tb * 8192;
    unsigned short* VtB = KsB + 4096;
    const int kk0 = T * 64;
    int row = wid * 8 + (lane >> 3);
    int sc = ((lane & 7) * 16) ^ ((row & 7) << 4);
    g2l16((const char*)(kn + (tok0 + kk0 + row) * 256 + hv * 64) + sc, (char*)KsB + wid * 1024);
    g2l16((const char*)(vtb + (size_t)row * 2048 + kk0) + sc, (char*)VtB + wid * 1024);
  };

  auto qk_tile = [&](int tb, f32x16* s) {
    const char* kbase0 = (const char*)SMEM + tb * 16384;
#pragma unroll
    for (int kt = 0; kt < 2; ++kt) {
      const int krow = kt * 32 + l31;
      const char* kbase = kbase0 + krow * 128;
      const int ksw = (krow & 7) << 4;
      __builtin_amdgcn_s_setprio(1);
      bf16x8 kf = *(const bf16x8*)(kbase + ((hi * 16) ^ ksw));
      f32x16 a = __builtin_amdgcn_mfma_f32_32x32x16_bf16(kf, qf[0], zer, 0, 0, 0);
#pragma unroll
      for (int m = 1; m < 4; ++m) {
        kf = *(const bf16x8*)(kbase + ((m * 32 + hi * 16) ^ ksw));
        a = __builtin_amdgcn_mfma_f32_32x32x16_bf16(kf, qf[m], a, 0, 0, 0);
      }
      __builtin_amdgcn_s_setprio(0);
      s[kt] = a;
    }
  };

  auto mask_tile = [&](int t, f32x16* s) {
    const int k0 = t * 64;
#pragma unroll
    for (int kt = 0; kt < 2; ++kt)
#pragma unroll
      for (int r = 0; r < 16; ++r) {
        int key = k0 + kt * 32 + (r & 3) + 8 * (r >> 2) + 4 * hi;
        if (key > qglob) s[kt][r] = -INFINITY;
      }
  };

  auto softmax_cvt = [&](f32x16* s, i32x4* paw) {
#pragma unroll
    for (int kt = 0; kt < 2; ++kt)
#pragma unroll
      for (int r = 0; r < 16; ++r) s[kt][r] = fexp2(s[kt][r]);
#pragma unroll
    for (int kt = 0; kt < 2; ++kt)
#pragma unroll
      for (int half = 0; half < 2; ++half) {
        int bs = half * 8;
        unsigned int a0 = cvtpk(s[kt][bs + 0], s[kt][bs + 1]);
        unsigned int a1 = cvtpk(s[kt][bs + 2], s[kt][bs + 3]);
        unsigned int b0 = cvtpk(s[kt][bs + 4], s[kt][bs + 5]);
        unsigned int b1 = cvtpk(s[kt][bs + 6], s[kt][bs + 7]);
        i32x2 r0 = __builtin_amdgcn_permlane32_swap((int)a0, (int)b0, false, false);
        i32x2 r1 = __builtin_amdgcn_permlane32_swap((int)a1, (int)b1, false, false);
        i32x4 w;
        w[0] = r0[0]; w[1] = r1[0]; w[2] = r0[1]; w[3] = r1[1];
        paw[kt * 2 + half] = w;
      }
  };

  auto pv_tile = [&](int tb, const i32x4* paw) {
    const char* vbase0 = (const char*)SMEM + tb * 16384 + 8192;
    __builtin_amdgcn_s_setprio(1);
#pragma unroll
    for (int db = 0; db < 2; ++db) {
      const int vrow = db * 32 + l31;
      const char* vbase = vbase0 + vrow * 128;
      const int vsw = (vrow & 7) << 4;
#pragma unroll
      for (int ks = 0; ks < 4; ++ks) {
        bf16x8 vf = *(const bf16x8*)(vbase + ((ks * 32 + hi * 16) ^ vsw));
        oacc[db] = __builtin_amdgcn_mfma_f32_32x32x16_bf16(
            vf, __builtin_bit_cast(bf16x8, paw[ks]), oacc[db], 0, 0, 0);
      }
    }
#pragma unroll
    for (int ks = 0; ks < 4; ++ks)
      lacc = __builtin_amdgcn_mfma_f32_32x32x16_bf16(
          ones, __builtin_bit_cast(bf16x8, paw[ks]), lacc, 0, 0, 0);
    __builtin_amdgcn_s_setprio(0);
  };

  const int npair = 2 * qcx + 2;  // nt = 4*qcx + 4 tiles

  stage(0, 0);
  stage(1, 1);
  __syncthreads();

  for (int p = 0; p < npair; ++p) {
    const int pb = (p & 1) << 1;   // tile-bufs pb, pb|1
    if (p + 1 < npair) {
      stage(2 * p + 2, pb ^ 2);
      stage(2 * p + 3, (pb ^ 2) | 1);
    }
    const int t0 = 2 * p;
    const bool visa = (t0 <= tdiag), visb = (t0 + 1 <= tdiag);
    const bool domask = (p >= npair - 2);
    f32x16 sa[2], sb[2];
    if (visa) qk_tile(pb, sa);
    if (visb) qk_tile(pb | 1, sb);
    if (domask) {
      if (visa) mask_tile(t0, sa);
      if (visb) mask_tile(t0 + 1, sb);
    }
    i32x4 pawa[4], pawb[4];
    if (visa) {
      softmax_cvt(sa, pawa);
      pv_tile(pb, pawa);
    }
    if (visb) {
      softmax_cvt(sb, pawb);   // overlaps pv_tile(pb) MFMAs
      pv_tile(pb | 1, pawb);
    }
    __syncthreads();           // drains prefetch + frees bufs pb,pb|1
  }

  // ---- epilogue: O^T -> per-wave LDS transpose -> coalesced row store ----
  const float inv = 1.0f / lacc[0];
  const int swl = (l31 & 7) << 4;
  char* obase = (char*)SMEM + wid * 4096;
#pragma unroll
  for (int db = 0; db < 2; ++db)
#pragma unroll
    for (int i = 0; i < 8; ++i) {
      int r = 2 * i;
      int dim = db * 32 + (r & 3) + 8 * (r >> 2) + 4 * hi;
      unsigned int w = (unsigned int)f2bf(oacc[db][r] * inv) |
                       ((unsigned int)f2bf(oacc[db][r + 1] * inv) << 16);
      *(unsigned int*)(obase + l31 * 128 + ((dim * 2) ^ swl)) = w;
    }
  __syncthreads();
#pragma unroll
  for (int it = 0; it < 4; ++it) {
    int cc = it * 2 + hi;
    i32x4 w = *(const i32x4*)(obase + l31 * 128 + ((cc * 16) ^ swl));
    *(i32x4*)(yb + (tok0 + q0w + l31) * 1024 + h * 64 + cc * 8) = w;
  }
}

// ---------------- launch ----------------
extern "C" void kernel_launch(void* const* d_in, const int* in_sizes, int n_in,
                              void* d_out, int out_size, void* d_ws, size_t ws_size,
                              hipStream_t stream) {
  (void)in_sizes; (void)n_in; (void)out_size; (void)ws_size;
  const float* x  = (const float*)d_in[0];
  const float* Wq = (const float*)d_in[1];
  const float* Wk = (const float*)d_in[2];
  const float* Wv = (const float*)d_in[3];
  const float* Wo = (const float*)d_in[4];
  const float* qg = (const float*)d_in[5];

  char* ws = (char*)d_ws;
  unsigned short* xb   = (unsigned short*)(ws);             // 16 MB  [8192][1024]
  unsigned short* wcat = (unsigned short*)(ws + 16777216);  // 3 MB   [1536][1024]
  unsigned short* wob  = (unsigned short*)(ws + 19922944);  // 2 MB   [1024][1024]
  unsigned short* qn   = (unsigned short*)(ws + 22020096);  // 16 MB  [8192][1024]
  unsigned short* kn   = (unsigned short*)(ws + 38797312);  // 4 MB   [8192][256]
  unsigned short* yb   = xb;                                // alias: xb dead after k_qkv
  unsigned short* vt   = (unsigned short*)((char*)d_out + 25165824);  // 4 MB [16][64][2048]
  float2*         rope = (float2*)((char*)d_out + 29360128);          // 512 KB [2048][32]

  k_cvt_all<<<5632, 256, 0, stream>>>(x, Wq, Wk, Wv, Wo, xb, wcat, wob, rope);
  k_qkv<<<dim3(64, 12), 256, 0, stream>>>(xb, wcat, qg, rope, qn, kn, vt);
  k_attn2<<<512, 512, 0, stream>>>(qn, kn, vt, yb);
  k_gemm_bt<<<dim3(64, 8), 256, 0, stream>>>(yb, wob, (float*)d_out, 8192, 1024, 1024);
}